// Round 11
// baseline (423.025 us; speedup 1.0000x reference)
//
#include <hip/hip_runtime.h>
#include <hip/hip_bf16.h>

#define N_NODES 50000
#define N_EDGES 800000
#define DIM 128
#define SCAN_BLOCKS ((N_NODES + 255) / 256)   // 196
#define NGROUPS (N_NODES / 16)                 // 3125 (exact)
#define LROW2 132                              // LDS row stride (floats), half-dim epilogue

typedef __attribute__((ext_vector_type(8))) short frag8;
typedef __attribute__((ext_vector_type(4))) float f32x4;

// fp32 -> bf16 bits (RNE)
__device__ __forceinline__ ushort f2b(float f){
  uint u = __float_as_uint(f);
  return (ushort)((u + 0x7fffu + ((u >> 16) & 1u)) >> 16);
}
__device__ __forceinline__ float b2f(ushort h){
  return __uint_as_float(((uint)h) << 16);
}

// ---------------- CSR build (per launch; graph-capture safe) ----------------

__global__ __launch_bounds__(256) void hist_k(
    const int* __restrict__ dst, int* __restrict__ deg)
{
  int e = blockIdx.x * 256 + threadIdx.x;
  if (e < N_EDGES) atomicAdd(deg + dst[e], 1);
}

__global__ __launch_bounds__(256) void scan_part_k(
    const int* __restrict__ deg, int* __restrict__ excl,
    int* __restrict__ blocksum)
{
  int t = threadIdx.x, lane = t & 63, w = t >> 6;
  int idx = blockIdx.x * 256 + t;
  int v = (idx < N_NODES) ? deg[idx] : 0;
  int inc = v;
  #pragma unroll
  for (int off = 1; off < 64; off <<= 1) {
    int y = __shfl_up(inc, off, 64);
    if (lane >= off) inc += y;
  }
  __shared__ int wsum[4];
  if (lane == 63) wsum[w] = inc;
  __syncthreads();
  int wpre = 0;
  #pragma unroll
  for (int i = 0; i < 4; i++) if (i < w) wpre += wsum[i];
  if (idx < N_NODES) excl[idx] = wpre + inc - v;
  if (t == 255) blocksum[blockIdx.x] = wpre + inc;
}

__global__ __launch_bounds__(256) void scan_tops_k(
    const int* __restrict__ blocksum, int* __restrict__ tops)
{
  int t = threadIdx.x, lane = t & 63, w = t >> 6;
  int v = (t < SCAN_BLOCKS) ? blocksum[t] : 0;
  int inc = v;
  #pragma unroll
  for (int off = 1; off < 64; off <<= 1) {
    int y = __shfl_up(inc, off, 64);
    if (lane >= off) inc += y;
  }
  __shared__ int wsum[4];
  if (lane == 63) wsum[w] = inc;
  __syncthreads();
  int wpre = 0;
  #pragma unroll
  for (int i = 0; i < 4; i++) if (i < w) wpre += wsum[i];
  if (t < SCAN_BLOCKS) tops[t] = wpre + inc - v;
}

__global__ __launch_bounds__(256) void scan_add_k(
    const int* __restrict__ excl, const int* __restrict__ tops,
    int* __restrict__ row_start, int* __restrict__ cursor,
    int* __restrict__ csr_src)
{
  int idx = blockIdx.x * 256 + threadIdx.x;
  if (idx < N_NODES) {
    int r = excl[idx] + tops[blockIdx.x];
    row_start[idx] = r;
    cursor[idx] = r;
  }
  if (idx == 0) row_start[N_NODES] = N_EDGES;
  // zero-pad csr_src tail so gather can over-read without clamping
  if (blockIdx.x == 0 && threadIdx.x < 128) csr_src[N_EDGES + threadIdx.x] = 0;
}

__global__ __launch_bounds__(256) void scatter_k(
    const int* __restrict__ src, const int* __restrict__ dst,
    int* __restrict__ cursor, int* __restrict__ csr_src)
{
  int e = blockIdx.x * 256 + threadIdx.x;
  if (e >= N_EDGES) return;
  int pos = atomicAdd(cursor + dst[e], 1);
  csr_src[pos] = src[e];
}

// ---------------- W fragment prep ----------------
// B-frag: lane holds B[k=(lane>>4)*8+j][n=lane&15].
// wb[((layer*4 + C)*16 + g)*64 + lane][8]; combined dim: <128 -> Wl, else Wr.
__global__ __launch_bounds__(64) void prep_w(
    const float* __restrict__ Wl1, const float* __restrict__ Wr1,
    const float* __restrict__ Wl2, const float* __restrict__ Wr2,
    ushort* __restrict__ wbh, ushort* __restrict__ wbl)
{
  int bid = blockIdx.x;            // 2 layers * 4 C * 16 g = 128 blocks
  int layer = bid >> 6, rest = bid & 63;
  int C = rest >> 4, g = rest & 15;
  int lane = threadIdx.x;
  int m = lane & 15, q = lane >> 4;
  int dim = g*16 + m;
  const float* W = layer ? (dim < 128 ? Wl2 : Wr2) : (dim < 128 ? Wl1 : Wr1);
  int dcol = dim & 127;
  ushort h[8], l[8];
  #pragma unroll
  for (int j = 0; j < 8; j++) {
    int k = C*32 + q*8 + j;
    float v = W[(size_t)k*DIM + dcol];
    h[j] = f2b(v);
    l[j] = f2b(v - b2f(h[j]));
  }
  size_t off = ((size_t)bid*64 + lane)*8;
  *(frag8*)(wbh + off) = *(frag8*)h;
  *(frag8*)(wbl + off) = *(frag8*)l;
}

// ---------------- MFMA dual GEMM (prep_x fused) ----------------
// Wave = 16 nodes (group G) x 256 combined dims (16 tiles of 16x16).
// A-fragments built on the fly from fp32 x (lane m=lane&15 row, q=lane>>4
// k-octet) -- split precision C = Ah*Bh + Ah*Bl + Al*Bh, fp32 acc.
// Epilogue: per-wave LDS transpose in 2 half-dim rounds (34 KB LDS).
__global__ __launch_bounds__(256) void gemm_mfma(
    const float* __restrict__ x,
    const ushort* __restrict__ wbh, const ushort* __restrict__ wbl,
    const float* __restrict__ bl, const float* __restrict__ br,
    float* __restrict__ xl, float* __restrict__ xr)
{
  __shared__ float lds[4][16*LROW2];   // 33.8 KB
  int wv = threadIdx.x >> 6, lane = threadIdx.x & 63;
  int G = blockIdx.x * 4 + wv;
  if (G >= NGROUPS) return;

  int m = lane & 15, q = lane >> 4;
  const float* xrow = x + (size_t)(G*16 + m)*DIM + q*8;

  f32x4 acc[16];
  #pragma unroll
  for (int g = 0; g < 16; g++) acc[g] = (f32x4)(0.f);

  #pragma unroll 1
  for (int C = 0; C < 4; C++) {
    float v[8];
    *(float4*)(v)     = *(const float4*)(xrow + C*32);
    *(float4*)(v + 4) = *(const float4*)(xrow + C*32 + 4);
    ushort h8[8], l8[8];
    #pragma unroll
    for (int j = 0; j < 8; j++) {
      h8[j] = f2b(v[j]);
      l8[j] = f2b(v[j] - b2f(h8[j]));
    }
    frag8 ah = *(frag8*)h8;
    frag8 al = *(frag8*)l8;
    #pragma unroll
    for (int g = 0; g < 16; g++) {
      size_t boff = ((size_t)(C*16 + g)*64 + lane)*8;
      frag8 bh = *(const frag8*)(wbh + boff);
      frag8 bo = *(const frag8*)(wbl + boff);
      acc[g] = __builtin_amdgcn_mfma_f32_16x16x32_bf16(ah, bh, acc[g], 0, 0, 0);
      acc[g] = __builtin_amdgcn_mfma_f32_16x16x32_bf16(ah, bo, acc[g], 0, 0, 0);
      acc[g] = __builtin_amdgcn_mfma_f32_16x16x32_bf16(al, bh, acc[g], 0, 0, 0);
    }
  }

  // C/D layout: col = lane&15 (dim-in-tile), row = (lane>>4)*4 + reg (node).
  // Two rounds: dims 0..127 -> xl, dims 128..255 -> xr. Same-wave LDS only.
  float* wlds = lds[wv];
  int dcol = (lane & 31) * 4;
  int rowsel = lane >> 5;
  #pragma unroll
  for (int half = 0; half < 2; half++) {
    #pragma unroll
    for (int g = 0; g < 8; g++) {
      #pragma unroll
      for (int r = 0; r < 4; r++)
        wlds[(q*4 + r)*LROW2 + g*16 + m] = acc[half*8 + g][r];
    }
    const float* B = half ? br : bl;
    float* outp = half ? xr : xl;
    float4 bv = *(const float4*)(B + dcol);
    #pragma unroll
    for (int it = 0; it < 8; it++) {
      int i = it*2 + rowsel;
      float4 vv = *(const float4*)(wlds + i*LROW2 + dcol);
      int node = G*16 + i;
      float4 o = make_float4(vv.x + bv.x, vv.y + bv.y, vv.z + bv.z, vv.w + bv.w);
      *(float4*)(outp + (size_t)node*DIM + dcol) = o;
    }
  }
}

// ---------------- fused edge phase: 32 lanes/node, 2 nodes/wave ------------
__global__ __launch_bounds__(256) void gat_gather(
    const float* __restrict__ xl, const float* __restrict__ xr,
    const int* __restrict__ row_start, const int* __restrict__ csr_src,
    const float* __restrict__ att, const float* __restrict__ bias,
    float* __restrict__ out)
{
  int wave = (blockIdx.x * 256 + threadIdx.x) >> 6;
  int lane = threadIdx.x & 63;
  int half = lane >> 5;
  int hl = lane & 31;
  int node = wave * 2 + half;
  if (node >= N_NODES) return;   // N even: whole wave exits together
  int r0 = row_start[node], r1 = row_start[node + 1];
  int deg = r1 - r0;
  int dmax = max(deg, __shfl_xor(deg, 32, 64));   // max over the 2 nodes

  float4 xrv = *(const float4*)(xr + (size_t)node*DIM + hl*4);
  float4 av  = *(const float4*)(att + hl*4);
  float m = -INFINITY, l = 0.f;
  float4 acc = make_float4(0.f, 0.f, 0.f, 0.f);

  for (int t = 0; t < dmax; t += 8) {
    float4 v[8];
    float p[8];
    #pragma unroll
    for (int j = 0; j < 8; j++) {
      int si = csr_src[r0 + t + j];          // csr_src zero-padded past E
      v[j] = *(const float4*)(xl + (size_t)si*DIM + hl*4);
    }
    #pragma unroll
    for (int j = 0; j < 8; j++) {
      float s0 = v[j].x + xrv.x, s1 = v[j].y + xrv.y;
      float s2 = v[j].z + xrv.z, s3 = v[j].w + xrv.w;
      s0 = fmaxf(s0, 0.2f*s0);               // leakyrelu = max(s, 0.2s)
      s1 = fmaxf(s1, 0.2f*s1);
      s2 = fmaxf(s2, 0.2f*s2);
      s3 = fmaxf(s3, 0.2f*s3);
      p[j] = av.x*s0 + av.y*s1 + av.z*s2 + av.w*s3;
    }
    #pragma unroll
    for (int o = 1; o <= 16; o <<= 1) {      // stays within 32-half
      #pragma unroll
      for (int j = 0; j < 8; j++) p[j] += __shfl_xor(p[j], o, 64);
    }
    #pragma unroll
    for (int j = 0; j < 8; j++) if (t + j >= deg) p[j] = -INFINITY;
    float pmax = p[0];
    #pragma unroll
    for (int j = 1; j < 8; j++) pmax = fmaxf(pmax, p[j]);
    float mn = fmaxf(m, pmax);
    float sc = (mn == -INFINITY) ? 0.f : __expf(m - mn);
    l *= sc; acc.x *= sc; acc.y *= sc; acc.z *= sc; acc.w *= sc;
    #pragma unroll
    for (int j = 0; j < 8; j++) {
      float w = (t + j < deg) ? __expf(p[j] - mn) : 0.f;
      l += w;
      acc.x = fmaf(w, v[j].x, acc.x);
      acc.y = fmaf(w, v[j].y, acc.y);
      acc.z = fmaf(w, v[j].z, acc.z);
      acc.w = fmaf(w, v[j].w, acc.w);
    }
    m = mn;
  }

  float denom = fmaxf(l, 1e-16f);
  float4 bv = *(const float4*)(bias + hl*4);
  float4 ov;
  ov.x = fmaxf(acc.x / denom + bv.x, 0.f);
  ov.y = fmaxf(acc.y / denom + bv.y, 0.f);
  ov.z = fmaxf(acc.z / denom + bv.z, 0.f);
  ov.w = fmaxf(acc.w / denom + bv.w, 0.f);
  *(float4*)(out + (size_t)node*DIM + hl*4) = ov;
}

extern "C" void kernel_launch(void* const* d_in, const int* in_sizes, int n_in,
                              void* d_out, int out_size, void* d_ws, size_t ws_size,
                              hipStream_t stream)
{
  const float* node_fts = (const float*)d_in[0];
  const int*  edge_index = (const int*)d_in[1];
  const float* Wl1 = (const float*)d_in[2];
  const float* bl1 = (const float*)d_in[3];
  const float* Wr1 = (const float*)d_in[4];
  const float* br1 = (const float*)d_in[5];
  const float* att1 = (const float*)d_in[6];
  const float* bias1 = (const float*)d_in[7];
  const float* Wl2 = (const float*)d_in[8];
  const float* bl2 = (const float*)d_in[9];
  const float* Wr2 = (const float*)d_in[10];
  const float* br2 = (const float*)d_in[11];
  const float* att2 = (const float*)d_in[12];
  const float* bias2 = (const float*)d_in[13];
  const int* src = edge_index;
  const int* dst = edge_index + N_EDGES;

  char* ws = (char*)d_ws;
  float* xl  = (float*)ws;                 ws += (size_t)N_NODES*DIM*4;
  float* xr  = (float*)ws;                 ws += (size_t)N_NODES*DIM*4;
  float* h   = (float*)ws;                 ws += (size_t)N_NODES*DIM*4;
  ushort* wbh = (ushort*)ws;               ws += 2*4*16*64*8*2;
  ushort* wbl = (ushort*)ws;               ws += 2*4*16*64*8*2;
  int* deg       = (int*)ws;               ws += N_NODES*4;
  int* row_start = (int*)ws;               ws += (N_NODES+1)*4;
  int* cursor    = (int*)ws;               ws += N_NODES*4;
  int* csr_src   = (int*)ws;               ws += ((size_t)N_EDGES + 128)*4;
  int* excl      = (int*)ws;               ws += N_NODES*4;
  int* blocksum  = (int*)ws;               ws += SCAN_BLOCKS*4;
  int* tops      = (int*)ws;

  const int W_LAYER = 4*16*64*8;           // ushorts per layer of wb

  int eb = (N_EDGES + 255) / 256;
  int gemm_blocks = (NGROUPS + 3) / 4;
  int gather_waves = (N_NODES + 1) / 2;
  int gather_blocks = (gather_waves + 3) / 4;

  // ---- CSR build ----
  hipMemsetAsync(deg, 0, N_NODES * sizeof(int), stream);
  hist_k<<<eb, 256, 0, stream>>>(dst, deg);
  scan_part_k<<<SCAN_BLOCKS, 256, 0, stream>>>(deg, excl, blocksum);
  scan_tops_k<<<1, 256, 0, stream>>>(blocksum, tops);
  scan_add_k<<<SCAN_BLOCKS, 256, 0, stream>>>(excl, tops, row_start, cursor, csr_src);
  scatter_k<<<eb, 256, 0, stream>>>(src, dst, cursor, csr_src);

  // ---- W fragment prep ----
  prep_w<<<128, 64, 0, stream>>>(Wl1, Wr1, Wl2, Wr2, wbh, wbl);

  // ---- layer 1 ----
  gemm_mfma<<<gemm_blocks, 256, 0, stream>>>(node_fts, wbh, wbl, bl1, br1, xl, xr);
  gat_gather<<<gather_blocks, 256, 0, stream>>>(xl, xr, row_start, csr_src,
                                                att1, bias1, h);
  // ---- layer 2 ----
  gemm_mfma<<<gemm_blocks, 256, 0, stream>>>(h, wbh + W_LAYER, wbl + W_LAYER,
                                             bl2, br2, xl, xr);
  gat_gather<<<gather_blocks, 256, 0, stream>>>(xl, xr, row_start, csr_src,
                                                att2, bias2, (float*)d_out);
}

// Round 12
// 337.026 us; speedup vs baseline: 1.2552x; 1.2552x over previous
//
#include <hip/hip_runtime.h>
#include <hip/hip_bf16.h>
#include <hip/hip_fp16.h>

#define N_NODES 50000
#define N_EDGES 800000
#define DIM 128
#define SCAN_BLOCKS ((N_NODES + 255) / 256)   // 196
#define NGROUPS (N_NODES / 16)                 // 3125 (exact)
#define LROW2 132                              // LDS row stride (floats)

typedef __attribute__((ext_vector_type(8))) short frag8;
typedef __attribute__((ext_vector_type(4))) float f32x4;

// fp32 -> bf16 bits (RNE)
__device__ __forceinline__ ushort f2b(float f){
  uint u = __float_as_uint(f);
  return (ushort)((u + 0x7fffu + ((u >> 16) & 1u)) >> 16);
}
__device__ __forceinline__ float b2f(ushort h){
  return __uint_as_float(((uint)h) << 16);
}

// ---------------- CSR build (per launch; graph-capture safe) ----------------

__global__ __launch_bounds__(256) void hist_k(
    const int* __restrict__ dst, int* __restrict__ deg)
{
  int e = blockIdx.x * 256 + threadIdx.x;
  if (e < N_EDGES) atomicAdd(deg + dst[e], 1);
}

__global__ __launch_bounds__(256) void scan_part_k(
    const int* __restrict__ deg, int* __restrict__ excl,
    int* __restrict__ blocksum)
{
  int t = threadIdx.x, lane = t & 63, w = t >> 6;
  int idx = blockIdx.x * 256 + t;
  int v = (idx < N_NODES) ? deg[idx] : 0;
  int inc = v;
  #pragma unroll
  for (int off = 1; off < 64; off <<= 1) {
    int y = __shfl_up(inc, off, 64);
    if (lane >= off) inc += y;
  }
  __shared__ int wsum[4];
  if (lane == 63) wsum[w] = inc;
  __syncthreads();
  int wpre = 0;
  #pragma unroll
  for (int i = 0; i < 4; i++) if (i < w) wpre += wsum[i];
  if (idx < N_NODES) excl[idx] = wpre + inc - v;
  if (t == 255) blocksum[blockIdx.x] = wpre + inc;
}

__global__ __launch_bounds__(256) void scan_tops_k(
    const int* __restrict__ blocksum, int* __restrict__ tops)
{
  int t = threadIdx.x, lane = t & 63, w = t >> 6;
  int v = (t < SCAN_BLOCKS) ? blocksum[t] : 0;
  int inc = v;
  #pragma unroll
  for (int off = 1; off < 64; off <<= 1) {
    int y = __shfl_up(inc, off, 64);
    if (lane >= off) inc += y;
  }
  __shared__ int wsum[4];
  if (lane == 63) wsum[w] = inc;
  __syncthreads();
  int wpre = 0;
  #pragma unroll
  for (int i = 0; i < 4; i++) if (i < w) wpre += wsum[i];
  if (t < SCAN_BLOCKS) tops[t] = wpre + inc - v;
}

__global__ __launch_bounds__(256) void scan_add_k(
    const int* __restrict__ excl, const int* __restrict__ tops,
    int* __restrict__ row_start, int* __restrict__ cursor)
{
  int idx = blockIdx.x * 256 + threadIdx.x;
  if (idx < N_NODES) {
    int r = excl[idx] + tops[blockIdx.x];
    row_start[idx] = r;
    cursor[idx] = r;
  }
  if (idx == 0) row_start[N_NODES] = N_EDGES;
}

__global__ __launch_bounds__(256) void scatter_k(
    const int* __restrict__ src, const int* __restrict__ dst,
    int* __restrict__ cursor, int* __restrict__ csr_src)
{
  int e = blockIdx.x * 256 + threadIdx.x;
  if (e >= N_EDGES) return;
  int pos = atomicAdd(cursor + dst[e], 1);
  csr_src[pos] = src[e];
}

// ---------------- W fragment prep ----------------
// B-frag: lane holds B[k=(lane>>4)*8+j][n=lane&15].
__global__ __launch_bounds__(64) void prep_w(
    const float* __restrict__ Wl1, const float* __restrict__ Wr1,
    const float* __restrict__ Wl2, const float* __restrict__ Wr2,
    ushort* __restrict__ wbh, ushort* __restrict__ wbl)
{
  int bid = blockIdx.x;            // 2 layers * 4 C * 16 g = 128 blocks
  int layer = bid >> 6, rest = bid & 63;
  int C = rest >> 4, g = rest & 15;
  int lane = threadIdx.x;
  int m = lane & 15, q = lane >> 4;
  int dim = g*16 + m;
  const float* W = layer ? (dim < 128 ? Wl2 : Wr2) : (dim < 128 ? Wl1 : Wr1);
  int dcol = dim & 127;
  ushort h[8], l[8];
  #pragma unroll
  for (int j = 0; j < 8; j++) {
    int k = C*32 + q*8 + j;
    float v = W[(size_t)k*DIM + dcol];
    h[j] = f2b(v);
    l[j] = f2b(v - b2f(h[j]));
  }
  size_t off = ((size_t)bid*64 + lane)*8;
  *(frag8*)(wbh + off) = *(frag8*)h;
  *(frag8*)(wbl + off) = *(frag8*)l;
}

// ---------------- MFMA dual GEMM (prep_x fused) ----------------
// Wave = 16 nodes x 256 combined dims. Split precision Ah*Bh+Ah*Bl+Al*Bh.
// Epilogue: LDS transpose; xl written as FP16 (gather-only consumer),
// xr written fp32.
__global__ __launch_bounds__(256) void gemm_mfma(
    const float* __restrict__ x,
    const ushort* __restrict__ wbh, const ushort* __restrict__ wbl,
    const float* __restrict__ bl, const float* __restrict__ br,
    __half* __restrict__ xlh, float* __restrict__ xr)
{
  __shared__ float lds[4][16*LROW2];   // 33.8 KB
  int wv = threadIdx.x >> 6, lane = threadIdx.x & 63;
  int G = blockIdx.x * 4 + wv;
  if (G >= NGROUPS) return;

  int m = lane & 15, q = lane >> 4;
  const float* xrow = x + (size_t)(G*16 + m)*DIM + q*8;

  f32x4 acc[16];
  #pragma unroll
  for (int g = 0; g < 16; g++) acc[g] = (f32x4)(0.f);

  #pragma unroll 1
  for (int C = 0; C < 4; C++) {
    float v[8];
    *(float4*)(v)     = *(const float4*)(xrow + C*32);
    *(float4*)(v + 4) = *(const float4*)(xrow + C*32 + 4);
    ushort h8[8], l8[8];
    #pragma unroll
    for (int j = 0; j < 8; j++) {
      h8[j] = f2b(v[j]);
      l8[j] = f2b(v[j] - b2f(h8[j]));
    }
    frag8 ah = *(frag8*)h8;
    frag8 al = *(frag8*)l8;
    #pragma unroll
    for (int g = 0; g < 16; g++) {
      size_t boff = ((size_t)(C*16 + g)*64 + lane)*8;
      frag8 bh = *(const frag8*)(wbh + boff);
      frag8 bo = *(const frag8*)(wbl + boff);
      acc[g] = __builtin_amdgcn_mfma_f32_16x16x32_bf16(ah, bh, acc[g], 0, 0, 0);
      acc[g] = __builtin_amdgcn_mfma_f32_16x16x32_bf16(ah, bo, acc[g], 0, 0, 0);
      acc[g] = __builtin_amdgcn_mfma_f32_16x16x32_bf16(al, bh, acc[g], 0, 0, 0);
    }
  }

  float* wlds = lds[wv];
  int dcol = (lane & 31) * 4;
  int rowsel = lane >> 5;
  #pragma unroll
  for (int half = 0; half < 2; half++) {
    #pragma unroll
    for (int g = 0; g < 8; g++) {
      #pragma unroll
      for (int r = 0; r < 4; r++)
        wlds[(q*4 + r)*LROW2 + g*16 + m] = acc[half*8 + g][r];
    }
    const float* B = half ? br : bl;
    float4 bv = *(const float4*)(B + dcol);
    #pragma unroll
    for (int it = 0; it < 8; it++) {
      int i = it*2 + rowsel;
      float4 vv = *(const float4*)(wlds + i*LROW2 + dcol);
      int node = G*16 + i;
      float4 o = make_float4(vv.x + bv.x, vv.y + bv.y, vv.z + bv.z, vv.w + bv.w);
      if (half == 0) {
        __half2 h0 = __floats2half2_rn(o.x, o.y);
        __half2 h1 = __floats2half2_rn(o.z, o.w);
        uint2 pk = make_uint2(*(uint*)&h0, *(uint*)&h1);
        *(uint2*)((ushort*)xlh + (size_t)node*DIM + dcol) = pk;
      } else {
        *(float4*)(xr + (size_t)node*DIM + dcol) = o;
      }
    }
  }
}

// ---------------- fused edge phase: 32 lanes/node, 2 nodes/wave ------------
// xl gathered in FP16 (half traffic); clamp duplicate-reads the LAST edge
// row (same-address -> cache hit; R11 over-read regressed FETCH by 43 MB).
__global__ __launch_bounds__(256) void gat_gather(
    const __half* __restrict__ xlh, const float* __restrict__ xr,
    const int* __restrict__ row_start, const int* __restrict__ csr_src,
    const float* __restrict__ att, const float* __restrict__ bias,
    float* __restrict__ out)
{
  int wave = (blockIdx.x * 256 + threadIdx.x) >> 6;
  int lane = threadIdx.x & 63;
  int half = lane >> 5;
  int hl = lane & 31;
  int node = wave * 2 + half;
  if (node >= N_NODES) return;   // N even: whole wave exits together
  int r0 = row_start[node], r1 = row_start[node + 1];
  int deg = r1 - r0;
  int last = r0 + deg - 1;
  int dmax = max(deg, __shfl_xor(deg, 32, 64));

  float4 xrv = *(const float4*)(xr + (size_t)node*DIM + hl*4);
  float4 av  = *(const float4*)(att + hl*4);
  float m = -INFINITY, l = 0.f;
  float4 acc = make_float4(0.f, 0.f, 0.f, 0.f);
  const ushort* xbase = (const ushort*)xlh + hl*4;

  for (int t = 0; t < dmax; t += 8) {
    float4 v[8];
    float p[8];
    #pragma unroll
    for (int j = 0; j < 8; j++) {
      int rr = r0 + t + j;
      int rc = rr <= last ? rr : last;
      rc = rc >= 0 ? rc : 0;                 // deg==0 safety
      int si = csr_src[rc];
      uint2 raw = *(const uint2*)(xbase + (size_t)si*DIM);
      float2 f0 = __half22float2(*(__half2*)&raw.x);
      float2 f1 = __half22float2(*(__half2*)&raw.y);
      v[j] = make_float4(f0.x, f0.y, f1.x, f1.y);
    }
    #pragma unroll
    for (int j = 0; j < 8; j++) {
      float s0 = v[j].x + xrv.x, s1 = v[j].y + xrv.y;
      float s2 = v[j].z + xrv.z, s3 = v[j].w + xrv.w;
      s0 = fmaxf(s0, 0.2f*s0);
      s1 = fmaxf(s1, 0.2f*s1);
      s2 = fmaxf(s2, 0.2f*s2);
      s3 = fmaxf(s3, 0.2f*s3);
      p[j] = av.x*s0 + av.y*s1 + av.z*s2 + av.w*s3;
    }
    #pragma unroll
    for (int o = 1; o <= 16; o <<= 1) {
      #pragma unroll
      for (int j = 0; j < 8; j++) p[j] += __shfl_xor(p[j], o, 64);
    }
    #pragma unroll
    for (int j = 0; j < 8; j++) if (t + j >= deg) p[j] = -INFINITY;
    float pmax = p[0];
    #pragma unroll
    for (int j = 1; j < 8; j++) pmax = fmaxf(pmax, p[j]);
    float mn = fmaxf(m, pmax);
    float sc = (mn == -INFINITY) ? 0.f : __expf(m - mn);
    l *= sc; acc.x *= sc; acc.y *= sc; acc.z *= sc; acc.w *= sc;
    #pragma unroll
    for (int j = 0; j < 8; j++) {
      float w = (t + j < deg) ? __expf(p[j] - mn) : 0.f;
      l += w;
      acc.x = fmaf(w, v[j].x, acc.x);
      acc.y = fmaf(w, v[j].y, acc.y);
      acc.z = fmaf(w, v[j].z, acc.z);
      acc.w = fmaf(w, v[j].w, acc.w);
    }
    m = mn;
  }

  float denom = fmaxf(l, 1e-16f);
  float4 bv = *(const float4*)(bias + hl*4);
  float4 ov;
  ov.x = fmaxf(acc.x / denom + bv.x, 0.f);
  ov.y = fmaxf(acc.y / denom + bv.y, 0.f);
  ov.z = fmaxf(acc.z / denom + bv.z, 0.f);
  ov.w = fmaxf(acc.w / denom + bv.w, 0.f);
  *(float4*)(out + (size_t)node*DIM + hl*4) = ov;
}

extern "C" void kernel_launch(void* const* d_in, const int* in_sizes, int n_in,
                              void* d_out, int out_size, void* d_ws, size_t ws_size,
                              hipStream_t stream)
{
  const float* node_fts = (const float*)d_in[0];
  const int*  edge_index = (const int*)d_in[1];
  const float* Wl1 = (const float*)d_in[2];
  const float* bl1 = (const float*)d_in[3];
  const float* Wr1 = (const float*)d_in[4];
  const float* br1 = (const float*)d_in[5];
  const float* att1 = (const float*)d_in[6];
  const float* bias1 = (const float*)d_in[7];
  const float* Wl2 = (const float*)d_in[8];
  const float* bl2 = (const float*)d_in[9];
  const float* Wr2 = (const float*)d_in[10];
  const float* br2 = (const float*)d_in[11];
  const float* att2 = (const float*)d_in[12];
  const float* bias2 = (const float*)d_in[13];
  const int* src = edge_index;
  const int* dst = edge_index + N_EDGES;

  char* ws = (char*)d_ws;
  __half* xlh = (__half*)ws;               ws += (size_t)N_NODES*DIM*2;
  float* xr  = (float*)ws;                 ws += (size_t)N_NODES*DIM*4;
  float* h   = (float*)ws;                 ws += (size_t)N_NODES*DIM*4;
  ushort* wbh = (ushort*)ws;               ws += 2*4*16*64*8*2;
  ushort* wbl = (ushort*)ws;               ws += 2*4*16*64*8*2;
  int* deg       = (int*)ws;               ws += N_NODES*4;
  int* row_start = (int*)ws;               ws += (N_NODES+1)*4;
  int* cursor    = (int*)ws;               ws += N_NODES*4;
  int* csr_src   = (int*)ws;               ws += (size_t)N_EDGES*4;
  int* excl      = (int*)ws;               ws += N_NODES*4;
  int* blocksum  = (int*)ws;               ws += SCAN_BLOCKS*4;
  int* tops      = (int*)ws;

  const int W_LAYER = 4*16*64*8;           // ushorts per layer of wb

  int eb = (N_EDGES + 255) / 256;
  int gemm_blocks = (NGROUPS + 3) / 4;
  int gather_waves = (N_NODES + 1) / 2;
  int gather_blocks = (gather_waves + 3) / 4;

  // ---- CSR build ----
  hipMemsetAsync(deg, 0, N_NODES * sizeof(int), stream);
  hist_k<<<eb, 256, 0, stream>>>(dst, deg);
  scan_part_k<<<SCAN_BLOCKS, 256, 0, stream>>>(deg, excl, blocksum);
  scan_tops_k<<<1, 256, 0, stream>>>(blocksum, tops);
  scan_add_k<<<SCAN_BLOCKS, 256, 0, stream>>>(excl, tops, row_start, cursor);
  scatter_k<<<eb, 256, 0, stream>>>(src, dst, cursor, csr_src);

  // ---- W fragment prep ----
  prep_w<<<128, 64, 0, stream>>>(Wl1, Wr1, Wl2, Wr2, wbh, wbl);

  // ---- layer 1 ----
  gemm_mfma<<<gemm_blocks, 256, 0, stream>>>(node_fts, wbh, wbl, bl1, br1, xlh, xr);
  gat_gather<<<gather_blocks, 256, 0, stream>>>(xlh, xr, row_start, csr_src,
                                                att1, bias1, h);
  // ---- layer 2 ----
  gemm_mfma<<<gemm_blocks, 256, 0, stream>>>(h, wbh + W_LAYER, wbl + W_LAYER,
                                             bl2, br2, xlh, xr);
  gat_gather<<<gather_blocks, 256, 0, stream>>>(xlh, xr, row_start, csr_src,
                                                att2, bias2, (float*)d_out);
}

// Round 13
// 321.923 us; speedup vs baseline: 1.3141x; 1.0469x over previous
//
#include <hip/hip_runtime.h>
#include <hip/hip_bf16.h>
#include <hip/hip_fp16.h>

#define N_NODES 50000
#define N_EDGES 800000
#define DIM 128
#define SCAN_BLOCKS ((N_NODES + 255) / 256)   // 196
#define NGROUPS (N_NODES / 16)                 // 3125 (exact)
#define LROW2 132                              // LDS row stride (floats)

typedef __attribute__((ext_vector_type(8))) short frag8;
typedef __attribute__((ext_vector_type(4))) float f32x4;

// fp32 -> bf16 bits (RNE)
__device__ __forceinline__ ushort f2b(float f){
  uint u = __float_as_uint(f);
  return (ushort)((u + 0x7fffu + ((u >> 16) & 1u)) >> 16);
}
__device__ __forceinline__ float b2f(ushort h){
  return __uint_as_float(((uint)h) << 16);
}

// ---------------- CSR build (per launch; graph-capture safe) ----------------

__global__ __launch_bounds__(256) void hist_k(
    const int* __restrict__ dst, int* __restrict__ deg)
{
  int e = blockIdx.x * 256 + threadIdx.x;
  if (e < N_EDGES) atomicAdd(deg + dst[e], 1);
}

__global__ __launch_bounds__(256) void scan_part_k(
    const int* __restrict__ deg, int* __restrict__ excl,
    int* __restrict__ blocksum)
{
  int t = threadIdx.x, lane = t & 63, w = t >> 6;
  int idx = blockIdx.x * 256 + t;
  int v = (idx < N_NODES) ? deg[idx] : 0;
  int inc = v;
  #pragma unroll
  for (int off = 1; off < 64; off <<= 1) {
    int y = __shfl_up(inc, off, 64);
    if (lane >= off) inc += y;
  }
  __shared__ int wsum[4];
  if (lane == 63) wsum[w] = inc;
  __syncthreads();
  int wpre = 0;
  #pragma unroll
  for (int i = 0; i < 4; i++) if (i < w) wpre += wsum[i];
  if (idx < N_NODES) excl[idx] = wpre + inc - v;
  if (t == 255) blocksum[blockIdx.x] = wpre + inc;
}

// scan_add with inline block-sum prefix (replaces scan_tops dispatch):
// each block sums blocksum[0..bid-1] itself (196 ints, L2-broadcast).
__global__ __launch_bounds__(256) void scan_add_k(
    const int* __restrict__ excl, const int* __restrict__ blocksum,
    int* __restrict__ row_start, int* __restrict__ cursor)
{
  int t = threadIdx.x, lane = t & 63, w = t >> 6;
  int bid = blockIdx.x;
  int v = (t < bid) ? blocksum[t] : 0;    // bid <= 195 < 256
  #pragma unroll
  for (int off = 32; off > 0; off >>= 1) v += __shfl_xor(v, off, 64);
  __shared__ int wsum[4];
  if (lane == 0) wsum[w] = v;
  __syncthreads();
  int tops = wsum[0] + wsum[1] + wsum[2] + wsum[3];
  int idx = bid * 256 + t;
  if (idx < N_NODES) {
    int r = excl[idx] + tops;
    row_start[idx] = r;
    cursor[idx] = r;
  }
  if (idx == 0) row_start[N_NODES] = N_EDGES;
}

__global__ __launch_bounds__(256) void scatter_k(
    const int* __restrict__ src, const int* __restrict__ dst,
    int* __restrict__ cursor, int* __restrict__ csr_src)
{
  int e = blockIdx.x * 256 + threadIdx.x;
  if (e >= N_EDGES) return;
  int pos = atomicAdd(cursor + dst[e], 1);
  csr_src[pos] = src[e];
}

// ---------------- W fragment prep ----------------
__global__ __launch_bounds__(64) void prep_w(
    const float* __restrict__ Wl1, const float* __restrict__ Wr1,
    const float* __restrict__ Wl2, const float* __restrict__ Wr2,
    ushort* __restrict__ wbh, ushort* __restrict__ wbl)
{
  int bid = blockIdx.x;            // 2 layers * 4 C * 16 g = 128 blocks
  int layer = bid >> 6, rest = bid & 63;
  int C = rest >> 4, g = rest & 15;
  int lane = threadIdx.x;
  int m = lane & 15, q = lane >> 4;
  int dim = g*16 + m;
  const float* W = layer ? (dim < 128 ? Wl2 : Wr2) : (dim < 128 ? Wl1 : Wr1);
  int dcol = dim & 127;
  ushort h[8], l[8];
  #pragma unroll
  for (int j = 0; j < 8; j++) {
    int k = C*32 + q*8 + j;
    float v = W[(size_t)k*DIM + dcol];
    h[j] = f2b(v);
    l[j] = f2b(v - b2f(h[j]));
  }
  size_t off = ((size_t)bid*64 + lane)*8;
  *(frag8*)(wbh + off) = *(frag8*)h;
  *(frag8*)(wbl + off) = *(frag8*)l;
}

// ---------------- MFMA dual GEMM (prep_x fused) ----------------
__global__ __launch_bounds__(256) void gemm_mfma(
    const float* __restrict__ x,
    const ushort* __restrict__ wbh, const ushort* __restrict__ wbl,
    const float* __restrict__ bl, const float* __restrict__ br,
    __half* __restrict__ xlh, float* __restrict__ xr)
{
  __shared__ float lds[4][16*LROW2];   // 33.8 KB
  int wv = threadIdx.x >> 6, lane = threadIdx.x & 63;
  int G = blockIdx.x * 4 + wv;
  if (G >= NGROUPS) return;

  int m = lane & 15, q = lane >> 4;
  const float* xrow = x + (size_t)(G*16 + m)*DIM + q*8;

  f32x4 acc[16];
  #pragma unroll
  for (int g = 0; g < 16; g++) acc[g] = (f32x4)(0.f);

  #pragma unroll 1
  for (int C = 0; C < 4; C++) {
    float v[8];
    *(float4*)(v)     = *(const float4*)(xrow + C*32);
    *(float4*)(v + 4) = *(const float4*)(xrow + C*32 + 4);
    ushort h8[8], l8[8];
    #pragma unroll
    for (int j = 0; j < 8; j++) {
      h8[j] = f2b(v[j]);
      l8[j] = f2b(v[j] - b2f(h8[j]));
    }
    frag8 ah = *(frag8*)h8;
    frag8 al = *(frag8*)l8;
    #pragma unroll
    for (int g = 0; g < 16; g++) {
      size_t boff = ((size_t)(C*16 + g)*64 + lane)*8;
      frag8 bh = *(const frag8*)(wbh + boff);
      frag8 bo = *(const frag8*)(wbl + boff);
      acc[g] = __builtin_amdgcn_mfma_f32_16x16x32_bf16(ah, bh, acc[g], 0, 0, 0);
      acc[g] = __builtin_amdgcn_mfma_f32_16x16x32_bf16(ah, bo, acc[g], 0, 0, 0);
      acc[g] = __builtin_amdgcn_mfma_f32_16x16x32_bf16(al, bh, acc[g], 0, 0, 0);
    }
  }

  float* wlds = lds[wv];
  int dcol = (lane & 31) * 4;
  int rowsel = lane >> 5;
  #pragma unroll
  for (int half = 0; half < 2; half++) {
    #pragma unroll
    for (int g = 0; g < 8; g++) {
      #pragma unroll
      for (int r = 0; r < 4; r++)
        wlds[(q*4 + r)*LROW2 + g*16 + m] = acc[half*8 + g][r];
    }
    const float* B = half ? br : bl;
    float4 bv = *(const float4*)(B + dcol);
    #pragma unroll
    for (int it = 0; it < 8; it++) {
      int i = it*2 + rowsel;
      float4 vv = *(const float4*)(wlds + i*LROW2 + dcol);
      int node = G*16 + i;
      float4 o = make_float4(vv.x + bv.x, vv.y + bv.y, vv.z + bv.z, vv.w + bv.w);
      if (half == 0) {
        __half2 h0 = __floats2half2_rn(o.x, o.y);
        __half2 h1 = __floats2half2_rn(o.z, o.w);
        uint2 pk = make_uint2(*(uint*)&h0, *(uint*)&h1);
        *(uint2*)((ushort*)xlh + (size_t)node*DIM + dcol) = pk;
      } else {
        *(float4*)(xr + (size_t)node*DIM + dcol) = o;
      }
    }
  }
}

// ---------------- fused edge phase: 16 lanes/node, 4 nodes/wave ------------
// lane&15 owns 8 dims (one uint4 fp16 load/row). No online max: softmax is
// shift-invariant and logits are O(+-6) -- Sum(exp(p)v)/Sum(exp(p)) directly.
// Batches of 4 edges are fully independent (no rescale chain).
__global__ __launch_bounds__(256) void gat_gather(
    const __half* __restrict__ xlh, const float* __restrict__ xr,
    const int* __restrict__ row_start, const int* __restrict__ csr_src,
    const float* __restrict__ att, const float* __restrict__ bias,
    float* __restrict__ out)
{
  int wave = (blockIdx.x * 256 + threadIdx.x) >> 6;
  int lane = threadIdx.x & 63;
  int q4 = lane >> 4;                 // node slot in wave
  int hl = lane & 15;                 // dim-sixteenth: dims hl*8..hl*8+7
  int node = wave * 4 + q4;           // N = 50000 = 12500 waves * 4, exact
  int r0 = row_start[node];
  int deg = row_start[node + 1] - r0;
  int last = r0 + deg - 1;
  int d1 = max(deg, __shfl_xor(deg, 16, 64));
  int dmax = max(d1, __shfl_xor(d1, 32, 64));

  const float* xrp = xr + (size_t)node*DIM + hl*8;
  float4 xr0 = *(const float4*)(xrp);
  float4 xr1 = *(const float4*)(xrp + 4);
  float4 av0 = *(const float4*)(att + hl*8);
  float4 av1 = *(const float4*)(att + hl*8 + 4);

  float l = 0.f;
  float a0=0,a1=0,a2=0,a3=0,a4=0,a5=0,a6=0,a7=0;
  const ushort* xbase = (const ushort*)xlh + hl*8;

  for (int t = 0; t < dmax; t += 4) {
    uint4 raw[4];
    #pragma unroll
    for (int j = 0; j < 4; j++) {
      int rr = r0 + t + j;
      int rc = rr <= last ? rr : last;
      rc = rc >= 0 ? rc : 0;                  // deg==0 safety
      int si = csr_src[rc];
      raw[j] = *(const uint4*)(xbase + (size_t)si*DIM);
    }
    #pragma unroll
    for (int j = 0; j < 4; j++) {
      float2 f0 = __half22float2(*(__half2*)&raw[j].x);
      float2 f1 = __half22float2(*(__half2*)&raw[j].y);
      float2 f2 = __half22float2(*(__half2*)&raw[j].z);
      float2 f3 = __half22float2(*(__half2*)&raw[j].w);
      float s0 = f0.x + xr0.x, s1 = f0.y + xr0.y;
      float s2 = f1.x + xr0.z, s3 = f1.y + xr0.w;
      float s4 = f2.x + xr1.x, s5 = f2.y + xr1.y;
      float s6 = f3.x + xr1.z, s7 = f3.y + xr1.w;
      s0 = fmaxf(s0, 0.2f*s0); s1 = fmaxf(s1, 0.2f*s1);
      s2 = fmaxf(s2, 0.2f*s2); s3 = fmaxf(s3, 0.2f*s3);
      s4 = fmaxf(s4, 0.2f*s4); s5 = fmaxf(s5, 0.2f*s5);
      s6 = fmaxf(s6, 0.2f*s6); s7 = fmaxf(s7, 0.2f*s7);
      float p = av0.x*s0;
      p = fmaf(av0.y, s1, p); p = fmaf(av0.z, s2, p);
      p = fmaf(av0.w, s3, p); p = fmaf(av1.x, s4, p);
      p = fmaf(av1.y, s5, p); p = fmaf(av1.z, s6, p);
      p = fmaf(av1.w, s7, p);
      #pragma unroll
      for (int o = 1; o <= 8; o <<= 1) p += __shfl_xor(p, o, 64);
      float w = (t + j < deg) ? __expf(p) : 0.f;
      l += w;
      a0 = fmaf(w, f0.x, a0); a1 = fmaf(w, f0.y, a1);
      a2 = fmaf(w, f1.x, a2); a3 = fmaf(w, f1.y, a3);
      a4 = fmaf(w, f2.x, a4); a5 = fmaf(w, f2.y, a5);
      a6 = fmaf(w, f3.x, a6); a7 = fmaf(w, f3.y, a7);
    }
  }

  float inv = 1.f / fmaxf(l, 1e-16f);
  const float* bp = bias + hl*8;
  float4 b0 = *(const float4*)(bp);
  float4 b1 = *(const float4*)(bp + 4);
  float4 o0, o1;
  o0.x = fmaxf(fmaf(a0, inv, b0.x), 0.f);
  o0.y = fmaxf(fmaf(a1, inv, b0.y), 0.f);
  o0.z = fmaxf(fmaf(a2, inv, b0.z), 0.f);
  o0.w = fmaxf(fmaf(a3, inv, b0.w), 0.f);
  o1.x = fmaxf(fmaf(a4, inv, b1.x), 0.f);
  o1.y = fmaxf(fmaf(a5, inv, b1.y), 0.f);
  o1.z = fmaxf(fmaf(a6, inv, b1.z), 0.f);
  o1.w = fmaxf(fmaf(a7, inv, b1.w), 0.f);
  float* op = out + (size_t)node*DIM + hl*8;
  *(float4*)(op)     = o0;
  *(float4*)(op + 4) = o1;
}

extern "C" void kernel_launch(void* const* d_in, const int* in_sizes, int n_in,
                              void* d_out, int out_size, void* d_ws, size_t ws_size,
                              hipStream_t stream)
{
  const float* node_fts = (const float*)d_in[0];
  const int*  edge_index = (const int*)d_in[1];
  const float* Wl1 = (const float*)d_in[2];
  const float* bl1 = (const float*)d_in[3];
  const float* Wr1 = (const float*)d_in[4];
  const float* br1 = (const float*)d_in[5];
  const float* att1 = (const float*)d_in[6];
  const float* bias1 = (const float*)d_in[7];
  const float* Wl2 = (const float*)d_in[8];
  const float* bl2 = (const float*)d_in[9];
  const float* Wr2 = (const float*)d_in[10];
  const float* br2 = (const float*)d_in[11];
  const float* att2 = (const float*)d_in[12];
  const float* bias2 = (const float*)d_in[13];
  const int* src = edge_index;
  const int* dst = edge_index + N_EDGES;

  char* ws = (char*)d_ws;
  __half* xlh = (__half*)ws;               ws += (size_t)N_NODES*DIM*2;
  float* xr  = (float*)ws;                 ws += (size_t)N_NODES*DIM*4;
  float* h   = (float*)ws;                 ws += (size_t)N_NODES*DIM*4;
  ushort* wbh = (ushort*)ws;               ws += 2*4*16*64*8*2;
  ushort* wbl = (ushort*)ws;               ws += 2*4*16*64*8*2;
  int* deg       = (int*)ws;               ws += N_NODES*4;
  int* row_start = (int*)ws;               ws += (N_NODES+1)*4;
  int* cursor    = (int*)ws;               ws += N_NODES*4;
  int* csr_src   = (int*)ws;               ws += (size_t)N_EDGES*4;
  int* excl      = (int*)ws;               ws += N_NODES*4;
  int* blocksum  = (int*)ws;               ws += SCAN_BLOCKS*4;

  const int W_LAYER = 4*16*64*8;           // ushorts per layer of wb

  int eb = (N_EDGES + 255) / 256;
  int gemm_blocks = (NGROUPS + 3) / 4;
  int gather_blocks = N_NODES / 16;        // 4 waves/block, 4 nodes/wave

  // ---- CSR build ----
  hipMemsetAsync(deg, 0, N_NODES * sizeof(int), stream);
  hist_k<<<eb, 256, 0, stream>>>(dst, deg);
  scan_part_k<<<SCAN_BLOCKS, 256, 0, stream>>>(deg, excl, blocksum);
  scan_add_k<<<SCAN_BLOCKS, 256, 0, stream>>>(excl, blocksum, row_start, cursor);
  scatter_k<<<eb, 256, 0, stream>>>(src, dst, cursor, csr_src);

  // ---- W fragment prep ----
  prep_w<<<128, 64, 0, stream>>>(Wl1, Wr1, Wl2, Wr2, wbh, wbl);

  // ---- layer 1 ----
  gemm_mfma<<<gemm_blocks, 256, 0, stream>>>(node_fts, wbh, wbl, bl1, br1, xlh, xr);
  gat_gather<<<gather_blocks, 256, 0, stream>>>(xlh, xr, row_start, csr_src,
                                                att1, bias1, h);
  // ---- layer 2 ----
  gemm_mfma<<<gemm_blocks, 256, 0, stream>>>(h, wbh + W_LAYER, wbl + W_LAYER,
                                             bl2, br2, xlh, xr);
  gat_gather<<<gather_blocks, 256, 0, stream>>>(xlh, xr, row_start, csr_src,
                                                att2, bias2, (float*)d_out);
}

// Round 14
// 270.117 us; speedup vs baseline: 1.5661x; 1.1918x over previous
//
#include <hip/hip_runtime.h>
#include <hip/hip_bf16.h>
#include <hip/hip_fp16.h>

#define N_NODES 50000
#define N_EDGES 800000
#define DIM 128
#define NGROUPS (N_NODES / 16)                 // 3125 (exact)
#define LROW2 132                              // LDS row stride (floats)
#define KBUCKET 196                            // buckets of 256 nodes (dst>>8)
#define BCAP 5120                              // bucket capacity (mean 4082, 16 sigma)
#define EPB 4000                               // edges per phase-A block (200 blocks)

typedef __attribute__((ext_vector_type(8))) short frag8;
typedef __attribute__((ext_vector_type(4))) float f32x4;

// fp32 -> bf16 bits (RNE)
__device__ __forceinline__ ushort f2b(float f){
  uint u = __float_as_uint(f);
  return (ushort)((u + 0x7fffu + ((u >> 16) & 1u)) >> 16);
}
__device__ __forceinline__ float b2f(ushort h){
  return __uint_as_float(((uint)h) << 16);
}

// ---------------- CSR build: two-phase bucket radix (no global data atomics) ----

// Phase A: LDS-count 196 buckets, reserve contiguous per-(block,bucket) slices
// (one global atomic per bucket per block = 38k total), write (src,dst) pairs.
__global__ __launch_bounds__(256) void bucket_scatter_k(
    const int* __restrict__ src, const int* __restrict__ dst,
    int* __restrict__ bucket_cnt, uint2* __restrict__ bucketdata)
{
  __shared__ int cnt[KBUCKET], base[KBUCKET], cur[KBUCKET];
  int tid = threadIdx.x;
  for (int t = tid; t < KBUCKET; t += 256) { cnt[t] = 0; cur[t] = 0; }
  __syncthreads();
  int e0 = blockIdx.x * EPB;
  for (int i = tid; i < EPB; i += 256)
    atomicAdd(&cnt[dst[e0 + i] >> 8], 1);
  __syncthreads();
  for (int t = tid; t < KBUCKET; t += 256)
    base[t] = atomicAdd(&bucket_cnt[t], cnt[t]);
  __syncthreads();
  for (int i = tid; i < EPB; i += 256) {
    int s = src[e0 + i], d = dst[e0 + i];
    int b = d >> 8;
    int r = atomicAdd(&cur[b], 1);
    bucketdata[(size_t)b * BCAP + base[b] + r] = make_uint2((uint)s, (uint)d);
  }
}

// exclusive scan of the 196 bucket counts (single small block)
__global__ __launch_bounds__(256) void bucket_scan_k(
    const int* __restrict__ bucket_cnt, int* __restrict__ bucket_base)
{
  int t = threadIdx.x, lane = t & 63, w = t >> 6;
  int v = (t < KBUCKET) ? bucket_cnt[t] : 0;
  int inc = v;
  #pragma unroll
  for (int off = 1; off < 64; off <<= 1) {
    int y = __shfl_up(inc, off, 64);
    if (lane >= off) inc += y;
  }
  __shared__ int wsum[4];
  if (lane == 63) wsum[w] = inc;
  __syncthreads();
  int wpre = 0;
  #pragma unroll
  for (int i = 0; i < 4; i++) if (i < w) wpre += wsum[i];
  if (t < KBUCKET) bucket_base[t] = wpre + inc - v;
}

// Phase B: one block per bucket. Sequential read of bucket pairs, 256-bin LDS
// hist + scan -> row_start (coalesced) and csr_src scatter into a 16 KB
// block-private region (full-line merge, single XCD).
__global__ __launch_bounds__(256) void bucket_csr_k(
    const int* __restrict__ bucket_cnt, const int* __restrict__ bucket_base,
    const uint2* __restrict__ bucketdata,
    int* __restrict__ row_start, int* __restrict__ csr_src)
{
  __shared__ int hist[256], cur[256];
  __shared__ int wsum[4];
  int b = blockIdx.x, tid = threadIdx.x;
  int cnt = bucket_cnt[b];
  int base_csr = bucket_base[b];
  int node0 = b << 8;
  hist[tid] = 0;
  __syncthreads();
  const uint2* bd = bucketdata + (size_t)b * BCAP;
  for (int i = tid; i < cnt; i += 256)
    atomicAdd(&hist[bd[i].y & 255], 1);
  __syncthreads();
  int v = hist[tid];
  int lane = tid & 63, w = tid >> 6;
  int inc = v;
  #pragma unroll
  for (int off = 1; off < 64; off <<= 1) {
    int y = __shfl_up(inc, off, 64);
    if (lane >= off) inc += y;
  }
  if (lane == 63) wsum[w] = inc;
  __syncthreads();
  int wpre = 0;
  #pragma unroll
  for (int i = 0; i < 4; i++) if (i < w) wpre += wsum[i];
  int excl = wpre + inc - v;
  int node = node0 + tid;
  if (node < N_NODES) row_start[node] = base_csr + excl;
  if (b == 0 && tid == 0) row_start[N_NODES] = N_EDGES;
  cur[tid] = excl;
  __syncthreads();
  for (int i = tid; i < cnt; i += 256) {
    uint2 p = bd[i];
    int r = atomicAdd(&cur[p.y & 255], 1);
    csr_src[base_csr + r] = (int)p.x;
  }
}

// ---------------- W fragment prep ----------------
__global__ __launch_bounds__(64) void prep_w(
    const float* __restrict__ Wl1, const float* __restrict__ Wr1,
    const float* __restrict__ Wl2, const float* __restrict__ Wr2,
    ushort* __restrict__ wbh, ushort* __restrict__ wbl)
{
  int bid = blockIdx.x;            // 2 layers * 4 C * 16 g = 128 blocks
  int layer = bid >> 6, rest = bid & 63;
  int C = rest >> 4, g = rest & 15;
  int lane = threadIdx.x;
  int m = lane & 15, q = lane >> 4;
  int dim = g*16 + m;
  const float* W = layer ? (dim < 128 ? Wl2 : Wr2) : (dim < 128 ? Wl1 : Wr1);
  int dcol = dim & 127;
  ushort h[8], l[8];
  #pragma unroll
  for (int j = 0; j < 8; j++) {
    int k = C*32 + q*8 + j;
    float v = W[(size_t)k*DIM + dcol];
    h[j] = f2b(v);
    l[j] = f2b(v - b2f(h[j]));
  }
  size_t off = ((size_t)bid*64 + lane)*8;
  *(frag8*)(wbh + off) = *(frag8*)h;
  *(frag8*)(wbl + off) = *(frag8*)l;
}

// ---------------- MFMA dual GEMM (prep_x fused) ----------------
__global__ __launch_bounds__(256) void gemm_mfma(
    const float* __restrict__ x,
    const ushort* __restrict__ wbh, const ushort* __restrict__ wbl,
    const float* __restrict__ bl, const float* __restrict__ br,
    __half* __restrict__ xlh, float* __restrict__ xr)
{
  __shared__ float lds[4][16*LROW2];   // 33.8 KB
  int wv = threadIdx.x >> 6, lane = threadIdx.x & 63;
  int G = blockIdx.x * 4 + wv;
  if (G >= NGROUPS) return;

  int m = lane & 15, q = lane >> 4;
  const float* xrow = x + (size_t)(G*16 + m)*DIM + q*8;

  f32x4 acc[16];
  #pragma unroll
  for (int g = 0; g < 16; g++) acc[g] = (f32x4)(0.f);

  #pragma unroll 1
  for (int C = 0; C < 4; C++) {
    float v[8];
    *(float4*)(v)     = *(const float4*)(xrow + C*32);
    *(float4*)(v + 4) = *(const float4*)(xrow + C*32 + 4);
    ushort h8[8], l8[8];
    #pragma unroll
    for (int j = 0; j < 8; j++) {
      h8[j] = f2b(v[j]);
      l8[j] = f2b(v[j] - b2f(h8[j]));
    }
    frag8 ah = *(frag8*)h8;
    frag8 al = *(frag8*)l8;
    #pragma unroll
    for (int g = 0; g < 16; g++) {
      size_t boff = ((size_t)(C*16 + g)*64 + lane)*8;
      frag8 bh = *(const frag8*)(wbh + boff);
      frag8 bo = *(const frag8*)(wbl + boff);
      acc[g] = __builtin_amdgcn_mfma_f32_16x16x32_bf16(ah, bh, acc[g], 0, 0, 0);
      acc[g] = __builtin_amdgcn_mfma_f32_16x16x32_bf16(ah, bo, acc[g], 0, 0, 0);
      acc[g] = __builtin_amdgcn_mfma_f32_16x16x32_bf16(al, bh, acc[g], 0, 0, 0);
    }
  }

  float* wlds = lds[wv];
  int dcol = (lane & 31) * 4;
  int rowsel = lane >> 5;
  #pragma unroll
  for (int half = 0; half < 2; half++) {
    #pragma unroll
    for (int g = 0; g < 8; g++) {
      #pragma unroll
      for (int r = 0; r < 4; r++)
        wlds[(q*4 + r)*LROW2 + g*16 + m] = acc[half*8 + g][r];
    }
    const float* B = half ? br : bl;
    float4 bv = *(const float4*)(B + dcol);
    #pragma unroll
    for (int it = 0; it < 8; it++) {
      int i = it*2 + rowsel;
      float4 vv = *(const float4*)(wlds + i*LROW2 + dcol);
      int node = G*16 + i;
      float4 o = make_float4(vv.x + bv.x, vv.y + bv.y, vv.z + bv.z, vv.w + bv.w);
      if (half == 0) {
        __half2 h0 = __floats2half2_rn(o.x, o.y);
        __half2 h1 = __floats2half2_rn(o.z, o.w);
        uint2 pk = make_uint2(*(uint*)&h0, *(uint*)&h1);
        *(uint2*)((ushort*)xlh + (size_t)node*DIM + dcol) = pk;
      } else {
        *(float4*)(xr + (size_t)node*DIM + dcol) = o;
      }
    }
  }
}

// ---------------- fused edge phase: 16 lanes/node, 4 nodes/wave ------------
__global__ __launch_bounds__(256) void gat_gather(
    const __half* __restrict__ xlh, const float* __restrict__ xr,
    const int* __restrict__ row_start, const int* __restrict__ csr_src,
    const float* __restrict__ att, const float* __restrict__ bias,
    float* __restrict__ out)
{
  int wave = (blockIdx.x * 256 + threadIdx.x) >> 6;
  int lane = threadIdx.x & 63;
  int q4 = lane >> 4;
  int hl = lane & 15;
  int node = wave * 4 + q4;           // N = 50000 = 12500 waves * 4, exact
  int r0 = row_start[node];
  int deg = row_start[node + 1] - r0;
  int last = r0 + deg - 1;
  int d1 = max(deg, __shfl_xor(deg, 16, 64));
  int dmax = max(d1, __shfl_xor(d1, 32, 64));

  const float* xrp = xr + (size_t)node*DIM + hl*8;
  float4 xr0 = *(const float4*)(xrp);
  float4 xr1 = *(const float4*)(xrp + 4);
  float4 av0 = *(const float4*)(att + hl*8);
  float4 av1 = *(const float4*)(att + hl*8 + 4);

  float l = 0.f;
  float a0=0,a1=0,a2=0,a3=0,a4=0,a5=0,a6=0,a7=0;
  const ushort* xbase = (const ushort*)xlh + hl*8;

  for (int t = 0; t < dmax; t += 4) {
    uint4 raw[4];
    #pragma unroll
    for (int j = 0; j < 4; j++) {
      int rr = r0 + t + j;
      int rc = rr <= last ? rr : last;
      rc = rc >= 0 ? rc : 0;                  // deg==0 safety
      int si = csr_src[rc];
      raw[j] = *(const uint4*)(xbase + (size_t)si*DIM);
    }
    #pragma unroll
    for (int j = 0; j < 4; j++) {
      float2 f0 = __half22float2(*(__half2*)&raw[j].x);
      float2 f1 = __half22float2(*(__half2*)&raw[j].y);
      float2 f2 = __half22float2(*(__half2*)&raw[j].z);
      float2 f3 = __half22float2(*(__half2*)&raw[j].w);
      float s0 = f0.x + xr0.x, s1 = f0.y + xr0.y;
      float s2 = f1.x + xr0.z, s3 = f1.y + xr0.w;
      float s4 = f2.x + xr1.x, s5 = f2.y + xr1.y;
      float s6 = f3.x + xr1.z, s7 = f3.y + xr1.w;
      s0 = fmaxf(s0, 0.2f*s0); s1 = fmaxf(s1, 0.2f*s1);
      s2 = fmaxf(s2, 0.2f*s2); s3 = fmaxf(s3, 0.2f*s3);
      s4 = fmaxf(s4, 0.2f*s4); s5 = fmaxf(s5, 0.2f*s5);
      s6 = fmaxf(s6, 0.2f*s6); s7 = fmaxf(s7, 0.2f*s7);
      float p = av0.x*s0;
      p = fmaf(av0.y, s1, p); p = fmaf(av0.z, s2, p);
      p = fmaf(av0.w, s3, p); p = fmaf(av1.x, s4, p);
      p = fmaf(av1.y, s5, p); p = fmaf(av1.z, s6, p);
      p = fmaf(av1.w, s7, p);
      #pragma unroll
      for (int o = 1; o <= 8; o <<= 1) p += __shfl_xor(p, o, 64);
      float w = (t + j < deg) ? __expf(p) : 0.f;
      l += w;
      a0 = fmaf(w, f0.x, a0); a1 = fmaf(w, f0.y, a1);
      a2 = fmaf(w, f1.x, a2); a3 = fmaf(w, f1.y, a3);
      a4 = fmaf(w, f2.x, a4); a5 = fmaf(w, f2.y, a5);
      a6 = fmaf(w, f3.x, a6); a7 = fmaf(w, f3.y, a7);
    }
  }

  float inv = 1.f / fmaxf(l, 1e-16f);
  const float* bp = bias + hl*8;
  float4 b0 = *(const float4*)(bp);
  float4 b1 = *(const float4*)(bp + 4);
  float4 o0, o1;
  o0.x = fmaxf(fmaf(a0, inv, b0.x), 0.f);
  o0.y = fmaxf(fmaf(a1, inv, b0.y), 0.f);
  o0.z = fmaxf(fmaf(a2, inv, b0.z), 0.f);
  o0.w = fmaxf(fmaf(a3, inv, b0.w), 0.f);
  o1.x = fmaxf(fmaf(a4, inv, b1.x), 0.f);
  o1.y = fmaxf(fmaf(a5, inv, b1.y), 0.f);
  o1.z = fmaxf(fmaf(a6, inv, b1.z), 0.f);
  o1.w = fmaxf(fmaf(a7, inv, b1.w), 0.f);
  float* op = out + (size_t)node*DIM + hl*8;
  *(float4*)(op)     = o0;
  *(float4*)(op + 4) = o1;
}

extern "C" void kernel_launch(void* const* d_in, const int* in_sizes, int n_in,
                              void* d_out, int out_size, void* d_ws, size_t ws_size,
                              hipStream_t stream)
{
  const float* node_fts = (const float*)d_in[0];
  const int*  edge_index = (const int*)d_in[1];
  const float* Wl1 = (const float*)d_in[2];
  const float* bl1 = (const float*)d_in[3];
  const float* Wr1 = (const float*)d_in[4];
  const float* br1 = (const float*)d_in[5];
  const float* att1 = (const float*)d_in[6];
  const float* bias1 = (const float*)d_in[7];
  const float* Wl2 = (const float*)d_in[8];
  const float* bl2 = (const float*)d_in[9];
  const float* Wr2 = (const float*)d_in[10];
  const float* br2 = (const float*)d_in[11];
  const float* att2 = (const float*)d_in[12];
  const float* bias2 = (const float*)d_in[13];
  const int* src = edge_index;
  const int* dst = edge_index + N_EDGES;

  char* ws = (char*)d_ws;
  __half* xlh = (__half*)ws;               ws += (size_t)N_NODES*DIM*2;
  float* xr  = (float*)ws;                 ws += (size_t)N_NODES*DIM*4;
  float* h   = (float*)ws;                 ws += (size_t)N_NODES*DIM*4;
  ushort* wbh = (ushort*)ws;               ws += 2*4*16*64*8*2;
  ushort* wbl = (ushort*)ws;               ws += 2*4*16*64*8*2;
  int* row_start   = (int*)ws;             ws += (N_NODES+1)*4;
  int* csr_src     = (int*)ws;             ws += (size_t)N_EDGES*4;
  int* bucket_cnt  = (int*)ws;             ws += KBUCKET*4;
  int* bucket_base = (int*)ws;             ws += KBUCKET*4;
  uint2* bucketdata = (uint2*)ws;          ws += (size_t)KBUCKET*BCAP*8;

  const int W_LAYER = 4*16*64*8;           // ushorts per layer of wb

  int gemm_blocks = (NGROUPS + 3) / 4;
  int gather_blocks = N_NODES / 16;        // 4 waves/block, 4 nodes/wave

  // ---- CSR build (two-phase bucket radix) ----
  hipMemsetAsync(bucket_cnt, 0, KBUCKET * sizeof(int), stream);
  bucket_scatter_k<<<N_EDGES/EPB, 256, 0, stream>>>(src, dst, bucket_cnt, bucketdata);
  bucket_scan_k<<<1, 256, 0, stream>>>(bucket_cnt, bucket_base);
  bucket_csr_k<<<KBUCKET, 256, 0, stream>>>(bucket_cnt, bucket_base, bucketdata,
                                            row_start, csr_src);

  // ---- W fragment prep ----
  prep_w<<<128, 64, 0, stream>>>(Wl1, Wr1, Wl2, Wr2, wbh, wbl);

  // ---- layer 1 ----
  gemm_mfma<<<gemm_blocks, 256, 0, stream>>>(node_fts, wbh, wbl, bl1, br1, xlh, xr);
  gat_gather<<<gather_blocks, 256, 0, stream>>>(xlh, xr, row_start, csr_src,
                                                att1, bias1, h);
  // ---- layer 2 ----
  gemm_mfma<<<gemm_blocks, 256, 0, stream>>>(h, wbh + W_LAYER, wbl + W_LAYER,
                                             bl2, br2, xlh, xr);
  gat_gather<<<gather_blocks, 256, 0, stream>>>(xlh, xr, row_start, csr_src,
                                                att2, bias2, (float*)d_out);
}

// Round 15
// 251.884 us; speedup vs baseline: 1.6794x; 1.0724x over previous
//
#include <hip/hip_runtime.h>
#include <hip/hip_bf16.h>
#include <hip/hip_fp16.h>

#define N_NODES 50000
#define N_EDGES 800000
#define DIM 128
#define NGROUPS (N_NODES / 16)                 // 3125 (exact)
#define LROW2 132                              // LDS row stride (floats)
#define KBUCKET 196                            // buckets of 256 nodes (dst>>8)
#define BCAP 5120                              // bucket capacity (mean 4082, 16 sigma)
#define EPB 4000                               // edges per phase-A block (200 blocks)

typedef __attribute__((ext_vector_type(8))) short frag8;
typedef __attribute__((ext_vector_type(4))) float f32x4;
typedef _Float16 h2 __attribute__((ext_vector_type(2)));

__device__ __forceinline__ h2 u2h(uint u){ union{uint u; h2 h;} c; c.u = u; return c.h; }

// fp32 -> bf16 bits (RNE)
__device__ __forceinline__ ushort f2b(float f){
  uint u = __float_as_uint(f);
  return (ushort)((u + 0x7fffu + ((u >> 16) & 1u)) >> 16);
}
__device__ __forceinline__ float b2f(ushort h){
  return __uint_as_float(((uint)h) << 16);
}

// ---------------- CSR build: two-phase bucket radix ----------------

// Phase A: LDS-count 196 buckets, reserve contiguous per-(block,bucket) slices,
// write (src,dst) pairs into bucket regions.
__global__ __launch_bounds__(256) void bucket_scatter_k(
    const int* __restrict__ src, const int* __restrict__ dst,
    int* __restrict__ bucket_cnt, uint2* __restrict__ bucketdata)
{
  __shared__ int cnt[KBUCKET], base[KBUCKET], cur[KBUCKET];
  int tid = threadIdx.x;
  for (int t = tid; t < KBUCKET; t += 256) { cnt[t] = 0; cur[t] = 0; }
  __syncthreads();
  int e0 = blockIdx.x * EPB;
  for (int i = tid; i < EPB; i += 256)
    atomicAdd(&cnt[dst[e0 + i] >> 8], 1);
  __syncthreads();
  for (int t = tid; t < KBUCKET; t += 256)
    base[t] = atomicAdd(&bucket_cnt[t], cnt[t]);
  __syncthreads();
  for (int i = tid; i < EPB; i += 256) {
    int s = src[e0 + i], d = dst[e0 + i];
    int b = d >> 8;
    int r = atomicAdd(&cur[b], 1);
    bucketdata[(size_t)b * BCAP + base[b] + r] = make_uint2((uint)s, (uint)d);
  }
}

// Phase B: one block per bucket; computes its own csr base (196-sum), then
// 256-bin LDS hist + scan -> row_start + csr_src (block-private region).
__global__ __launch_bounds__(256) void bucket_csr_k(
    const int* __restrict__ bucket_cnt, const uint2* __restrict__ bucketdata,
    int* __restrict__ row_start, int* __restrict__ csr_src)
{
  __shared__ int hist[256], cur[256];
  __shared__ int wsumA[4], wsumB[4];
  int b = blockIdx.x, tid = threadIdx.x;
  int lane = tid & 63, w = tid >> 6;
  // base = sum(bucket_cnt[0..b-1])
  int vv = (tid < b) ? bucket_cnt[tid] : 0;
  #pragma unroll
  for (int off = 32; off > 0; off >>= 1) vv += __shfl_xor(vv, off, 64);
  if (lane == 0) wsumA[w] = vv;
  hist[tid] = 0;
  __syncthreads();
  int base_csr = wsumA[0] + wsumA[1] + wsumA[2] + wsumA[3];
  int cnt = bucket_cnt[b];
  int node0 = b << 8;
  const uint2* bd = bucketdata + (size_t)b * BCAP;
  for (int i = tid; i < cnt; i += 256)
    atomicAdd(&hist[bd[i].y & 255], 1);
  __syncthreads();
  int v = hist[tid];
  int inc = v;
  #pragma unroll
  for (int off = 1; off < 64; off <<= 1) {
    int y = __shfl_up(inc, off, 64);
    if (lane >= off) inc += y;
  }
  if (lane == 63) wsumB[w] = inc;
  __syncthreads();
  int wpre = 0;
  #pragma unroll
  for (int i = 0; i < 4; i++) if (i < w) wpre += wsumB[i];
  int excl = wpre + inc - v;
  int node = node0 + tid;
  if (node < N_NODES) row_start[node] = base_csr + excl;
  if (b == 0 && tid == 0) row_start[N_NODES] = N_EDGES;
  cur[tid] = excl;
  __syncthreads();
  for (int i = tid; i < cnt; i += 256) {
    uint2 p = bd[i];
    int r = atomicAdd(&cur[p.y & 255], 1);
    csr_src[base_csr + r] = (int)p.x;
  }
}

// ---------------- W fragment prep ----------------
__global__ __launch_bounds__(64) void prep_w(
    const float* __restrict__ Wl1, const float* __restrict__ Wr1,
    const float* __restrict__ Wl2, const float* __restrict__ Wr2,
    ushort* __restrict__ wbh, ushort* __restrict__ wbl)
{
  int bid = blockIdx.x;            // 2 layers * 4 C * 16 g = 128 blocks
  int layer = bid >> 6, rest = bid & 63;
  int C = rest >> 4, g = rest & 15;
  int lane = threadIdx.x;
  int m = lane & 15, q = lane >> 4;
  int dim = g*16 + m;
  const float* W = layer ? (dim < 128 ? Wl2 : Wr2) : (dim < 128 ? Wl1 : Wr1);
  int dcol = dim & 127;
  ushort h[8], l[8];
  #pragma unroll
  for (int j = 0; j < 8; j++) {
    int k = C*32 + q*8 + j;
    float v = W[(size_t)k*DIM + dcol];
    h[j] = f2b(v);
    l[j] = f2b(v - b2f(h[j]));
  }
  size_t off = ((size_t)bid*64 + lane)*8;
  *(frag8*)(wbh + off) = *(frag8*)h;
  *(frag8*)(wbl + off) = *(frag8*)l;
}

// ---------------- MFMA dual GEMM (prep_x fused) ----------------
// Epilogue: LDS transpose; BOTH xl and xr stored fp16 (gather-only consumers).
__global__ __launch_bounds__(256) void gemm_mfma(
    const float* __restrict__ x,
    const ushort* __restrict__ wbh, const ushort* __restrict__ wbl,
    const float* __restrict__ bl, const float* __restrict__ br,
    __half* __restrict__ xlh, __half* __restrict__ xrh)
{
  __shared__ float lds[4][16*LROW2];   // 33.8 KB
  int wv = threadIdx.x >> 6, lane = threadIdx.x & 63;
  int G = blockIdx.x * 4 + wv;
  if (G >= NGROUPS) return;

  int m = lane & 15, q = lane >> 4;
  const float* xrow = x + (size_t)(G*16 + m)*DIM + q*8;

  f32x4 acc[16];
  #pragma unroll
  for (int g = 0; g < 16; g++) acc[g] = (f32x4)(0.f);

  #pragma unroll 1
  for (int C = 0; C < 4; C++) {
    float v[8];
    *(float4*)(v)     = *(const float4*)(xrow + C*32);
    *(float4*)(v + 4) = *(const float4*)(xrow + C*32 + 4);
    ushort h8[8], l8[8];
    #pragma unroll
    for (int j = 0; j < 8; j++) {
      h8[j] = f2b(v[j]);
      l8[j] = f2b(v[j] - b2f(h8[j]));
    }
    frag8 ah = *(frag8*)h8;
    frag8 al = *(frag8*)l8;
    #pragma unroll
    for (int g = 0; g < 16; g++) {
      size_t boff = ((size_t)(C*16 + g)*64 + lane)*8;
      frag8 bh = *(const frag8*)(wbh + boff);
      frag8 bo = *(const frag8*)(wbl + boff);
      acc[g] = __builtin_amdgcn_mfma_f32_16x16x32_bf16(ah, bh, acc[g], 0, 0, 0);
      acc[g] = __builtin_amdgcn_mfma_f32_16x16x32_bf16(ah, bo, acc[g], 0, 0, 0);
      acc[g] = __builtin_amdgcn_mfma_f32_16x16x32_bf16(al, bh, acc[g], 0, 0, 0);
    }
  }

  float* wlds = lds[wv];
  int dcol = (lane & 31) * 4;
  int rowsel = lane >> 5;
  #pragma unroll
  for (int half = 0; half < 2; half++) {
    #pragma unroll
    for (int g = 0; g < 8; g++) {
      #pragma unroll
      for (int r = 0; r < 4; r++)
        wlds[(q*4 + r)*LROW2 + g*16 + m] = acc[half*8 + g][r];
    }
    const float* B = half ? br : bl;
    ushort* outh = half ? (ushort*)xrh : (ushort*)xlh;
    float4 bv = *(const float4*)(B + dcol);
    #pragma unroll
    for (int it = 0; it < 8; it++) {
      int i = it*2 + rowsel;
      float4 vv = *(const float4*)(wlds + i*LROW2 + dcol);
      int node = G*16 + i;
      __half2 h0 = __floats2half2_rn(vv.x + bv.x, vv.y + bv.y);
      __half2 h1 = __floats2half2_rn(vv.z + bv.z, vv.w + bv.w);
      uint2 pk = make_uint2(*(uint*)&h0, *(uint*)&h1);
      *(uint2*)(outh + (size_t)node*DIM + dcol) = pk;
    }
  }
}

// ---------------- fused edge phase: 16 lanes/node, 4 nodes/wave ------------
// Packed fp16: pk_add / pk_mul+pk_max (leaky) / v_dot2_f32_f16 dot /
// mix-precision fma accumulate. No online max (shift-invariant softmax).
__global__ __launch_bounds__(256) void gat_gather(
    const __half* __restrict__ xlh, const __half* __restrict__ xrh,
    const int* __restrict__ row_start, const int* __restrict__ csr_src,
    const float* __restrict__ att, const float* __restrict__ bias,
    float* __restrict__ out)
{
  int wave = (blockIdx.x * 256 + threadIdx.x) >> 6;
  int lane = threadIdx.x & 63;
  int q4 = lane >> 4;
  int hl = lane & 15;
  int node = wave * 4 + q4;           // N = 50000 = 12500 waves * 4, exact
  int r0 = row_start[node];
  int deg = row_start[node + 1] - r0;
  int last = r0 + deg - 1;
  int d1 = max(deg, __shfl_xor(deg, 16, 64));
  int dmax = max(d1, __shfl_xor(d1, 32, 64));

  uint4 rx = *(const uint4*)((const ushort*)xrh + (size_t)node*DIM + hl*8);
  h2 xr01 = u2h(rx.x), xr23 = u2h(rx.y), xr45 = u2h(rx.z), xr67 = u2h(rx.w);
  const float* ap = att + hl*8;
  float4 af0 = *(const float4*)(ap);
  float4 af1 = *(const float4*)(ap + 4);
  h2 a01 = {(_Float16)af0.x, (_Float16)af0.y};
  h2 a23 = {(_Float16)af0.z, (_Float16)af0.w};
  h2 a45 = {(_Float16)af1.x, (_Float16)af1.y};
  h2 a67 = {(_Float16)af1.z, (_Float16)af1.w};
  const h2 c02 = {(_Float16)0.2f, (_Float16)0.2f};

  float l = 0.f;
  float b0a=0,b1a=0,b2a=0,b3a=0,b4a=0,b5a=0,b6a=0,b7a=0;
  const ushort* xbase = (const ushort*)xlh + hl*8;

  for (int t = 0; t < dmax; t += 4) {
    uint4 raw[4];
    #pragma unroll
    for (int j = 0; j < 4; j++) {
      int rr = r0 + t + j;
      int rc = rr <= last ? rr : last;
      rc = rc >= 0 ? rc : 0;                  // deg==0 safety
      int si = csr_src[rc];
      raw[j] = *(const uint4*)(xbase + (size_t)si*DIM);
    }
    #pragma unroll
    for (int j = 0; j < 4; j++) {
      h2 v01 = u2h(raw[j].x), v23 = u2h(raw[j].y);
      h2 v45 = u2h(raw[j].z), v67 = u2h(raw[j].w);
      h2 s01 = v01 + xr01, s23 = v23 + xr23;
      h2 s45 = v45 + xr45, s67 = v67 + xr67;
      s01 = __builtin_elementwise_max(s01, s01 * c02);
      s23 = __builtin_elementwise_max(s23, s23 * c02);
      s45 = __builtin_elementwise_max(s45, s45 * c02);
      s67 = __builtin_elementwise_max(s67, s67 * c02);
      float p = __builtin_amdgcn_fdot2(s01, a01, 0.f, false);
      p = __builtin_amdgcn_fdot2(s23, a23, p, false);
      p = __builtin_amdgcn_fdot2(s45, a45, p, false);
      p = __builtin_amdgcn_fdot2(s67, a67, p, false);
      #pragma unroll
      for (int o = 1; o <= 8; o <<= 1) p += __shfl_xor(p, o, 64);
      float w = (t + j < deg) ? __expf(p) : 0.f;
      l += w;
      b0a = fmaf(w, (float)v01.x, b0a); b1a = fmaf(w, (float)v01.y, b1a);
      b2a = fmaf(w, (float)v23.x, b2a); b3a = fmaf(w, (float)v23.y, b3a);
      b4a = fmaf(w, (float)v45.x, b4a); b5a = fmaf(w, (float)v45.y, b5a);
      b6a = fmaf(w, (float)v67.x, b6a); b7a = fmaf(w, (float)v67.y, b7a);
    }
  }

  float inv = 1.f / fmaxf(l, 1e-16f);
  const float* bp = bias + hl*8;
  float4 c0 = *(const float4*)(bp);
  float4 c1 = *(const float4*)(bp + 4);
  float4 o0, o1;
  o0.x = fmaxf(fmaf(b0a, inv, c0.x), 0.f);
  o0.y = fmaxf(fmaf(b1a, inv, c0.y), 0.f);
  o0.z = fmaxf(fmaf(b2a, inv, c0.z), 0.f);
  o0.w = fmaxf(fmaf(b3a, inv, c0.w), 0.f);
  o1.x = fmaxf(fmaf(b4a, inv, c1.x), 0.f);
  o1.y = fmaxf(fmaf(b5a, inv, c1.y), 0.f);
  o1.z = fmaxf(fmaf(b6a, inv, c1.z), 0.f);
  o1.w = fmaxf(fmaf(b7a, inv, c1.w), 0.f);
  float* op = out + (size_t)node*DIM + hl*8;
  *(float4*)(op)     = o0;
  *(float4*)(op + 4) = o1;
}

extern "C" void kernel_launch(void* const* d_in, const int* in_sizes, int n_in,
                              void* d_out, int out_size, void* d_ws, size_t ws_size,
                              hipStream_t stream)
{
  const float* node_fts = (const float*)d_in[0];
  const int*  edge_index = (const int*)d_in[1];
  const float* Wl1 = (const float*)d_in[2];
  const float* bl1 = (const float*)d_in[3];
  const float* Wr1 = (const float*)d_in[4];
  const float* br1 = (const float*)d_in[5];
  const float* att1 = (const float*)d_in[6];
  const float* bias1 = (const float*)d_in[7];
  const float* Wl2 = (const float*)d_in[8];
  const float* bl2 = (const float*)d_in[9];
  const float* Wr2 = (const float*)d_in[10];
  const float* br2 = (const float*)d_in[11];
  const float* att2 = (const float*)d_in[12];
  const float* bias2 = (const float*)d_in[13];
  const int* src = edge_index;
  const int* dst = edge_index + N_EDGES;

  char* ws = (char*)d_ws;
  __half* xlh = (__half*)ws;               ws += (size_t)N_NODES*DIM*2;
  __half* xrh = (__half*)ws;               ws += (size_t)N_NODES*DIM*2;
  float* h   = (float*)ws;                 ws += (size_t)N_NODES*DIM*4;
  ushort* wbh = (ushort*)ws;               ws += 2*4*16*64*8*2;
  ushort* wbl = (ushort*)ws;               ws += 2*4*16*64*8*2;
  int* row_start   = (int*)ws;             ws += (N_NODES+1)*4;
  int* csr_src     = (int*)ws;             ws += (size_t)N_EDGES*4;
  int* bucket_cnt  = (int*)ws;             ws += KBUCKET*4;
  uint2* bucketdata = (uint2*)ws;          ws += (size_t)KBUCKET*BCAP*8;

  const int W_LAYER = 4*16*64*8;           // ushorts per layer of wb

  int gemm_blocks = (NGROUPS + 3) / 4;
  int gather_blocks = N_NODES / 16;        // 4 waves/block, 4 nodes/wave

  // ---- CSR build (two-phase bucket radix) ----
  hipMemsetAsync(bucket_cnt, 0, KBUCKET * sizeof(int), stream);
  bucket_scatter_k<<<N_EDGES/EPB, 256, 0, stream>>>(src, dst, bucket_cnt, bucketdata);
  bucket_csr_k<<<KBUCKET, 256, 0, stream>>>(bucket_cnt, bucketdata, row_start, csr_src);

  // ---- W fragment prep ----
  prep_w<<<128, 64, 0, stream>>>(Wl1, Wr1, Wl2, Wr2, wbh, wbl);

  // ---- layer 1 ----
  gemm_mfma<<<gemm_blocks, 256, 0, stream>>>(node_fts, wbh, wbl, bl1, br1, xlh, xrh);
  gat_gather<<<gather_blocks, 256, 0, stream>>>(xlh, xrh, row_start, csr_src,
                                                att1, bias1, h);
  // ---- layer 2 ----
  gemm_mfma<<<gemm_blocks, 256, 0, stream>>>(h, wbh + W_LAYER, wbl + W_LAYER,
                                             bl2, br2, xlh, xrh);
  gat_gather<<<gather_blocks, 256, 0, stream>>>(xlh, xrh, row_start, csr_src,
                                                att2, bias2, (float*)d_out);
}

// Round 16
// 248.575 us; speedup vs baseline: 1.7018x; 1.0133x over previous
//
#include <hip/hip_runtime.h>
#include <hip/hip_bf16.h>
#include <hip/hip_fp16.h>

#define N_NODES 50000
#define N_EDGES 800000
#define DIM 128
#define NGROUPS (N_NODES / 16)                 // 3125 (exact)
#define LROW2 132                              // LDS row stride (floats)
#define KBUCKET 196                            // buckets of 256 nodes (dst>>8)
#define BCAP 5120                              // bucket capacity (mean 4082, 16 sigma)
#define EPB 4000                               // edges per phase-A block (200 blocks)

typedef __attribute__((ext_vector_type(8))) _Float16 hfrag8;
typedef __attribute__((ext_vector_type(4))) float f32x4;
typedef _Float16 h2 __attribute__((ext_vector_type(2)));

__device__ __forceinline__ h2 u2h(uint u){ union{uint u; h2 h;} c; c.u = u; return c.h; }

// ---------------- CSR build: two-phase bucket radix ----------------

__global__ __launch_bounds__(256) void bucket_scatter_k(
    const int* __restrict__ src, const int* __restrict__ dst,
    int* __restrict__ bucket_cnt, uint2* __restrict__ bucketdata)
{
  __shared__ int cnt[KBUCKET], base[KBUCKET], cur[KBUCKET];
  int tid = threadIdx.x;
  for (int t = tid; t < KBUCKET; t += 256) { cnt[t] = 0; cur[t] = 0; }
  __syncthreads();
  int e0 = blockIdx.x * EPB;
  for (int i = tid; i < EPB; i += 256)
    atomicAdd(&cnt[dst[e0 + i] >> 8], 1);
  __syncthreads();
  for (int t = tid; t < KBUCKET; t += 256)
    base[t] = atomicAdd(&bucket_cnt[t], cnt[t]);
  __syncthreads();
  for (int i = tid; i < EPB; i += 256) {
    int s = src[e0 + i], d = dst[e0 + i];
    int b = d >> 8;
    int r = atomicAdd(&cur[b], 1);
    bucketdata[(size_t)b * BCAP + base[b] + r] = make_uint2((uint)s, (uint)d);
  }
}

__global__ __launch_bounds__(256) void bucket_csr_k(
    const int* __restrict__ bucket_cnt, const uint2* __restrict__ bucketdata,
    int* __restrict__ row_start, int* __restrict__ csr_src)
{
  __shared__ int hist[256], cur[256];
  __shared__ int wsumA[4], wsumB[4];
  int b = blockIdx.x, tid = threadIdx.x;
  int lane = tid & 63, w = tid >> 6;
  int vv = (tid < b) ? bucket_cnt[tid] : 0;
  #pragma unroll
  for (int off = 32; off > 0; off >>= 1) vv += __shfl_xor(vv, off, 64);
  if (lane == 0) wsumA[w] = vv;
  hist[tid] = 0;
  __syncthreads();
  int base_csr = wsumA[0] + wsumA[1] + wsumA[2] + wsumA[3];
  int cnt = bucket_cnt[b];
  int node0 = b << 8;
  const uint2* bd = bucketdata + (size_t)b * BCAP;
  for (int i = tid; i < cnt; i += 256)
    atomicAdd(&hist[bd[i].y & 255], 1);
  __syncthreads();
  int v = hist[tid];
  int inc = v;
  #pragma unroll
  for (int off = 1; off < 64; off <<= 1) {
    int y = __shfl_up(inc, off, 64);
    if (lane >= off) inc += y;
  }
  if (lane == 63) wsumB[w] = inc;
  __syncthreads();
  int wpre = 0;
  #pragma unroll
  for (int i = 0; i < 4; i++) if (i < w) wpre += wsumB[i];
  int excl = wpre + inc - v;
  int node = node0 + tid;
  if (node < N_NODES) row_start[node] = base_csr + excl;
  if (b == 0 && tid == 0) row_start[N_NODES] = N_EDGES;
  cur[tid] = excl;
  __syncthreads();
  for (int i = tid; i < cnt; i += 256) {
    uint2 p = bd[i];
    int r = atomicAdd(&cur[p.y & 255], 1);
    csr_src[base_csr + r] = (int)p.x;
  }
}

// ---------------- W fragment prep (fp16) ----------------
// B-frag: lane holds B[k=(lane>>4)*8+j][n=lane&15].
__global__ __launch_bounds__(64) void prep_w(
    const float* __restrict__ Wl1, const float* __restrict__ Wr1,
    const float* __restrict__ Wl2, const float* __restrict__ Wr2,
    _Float16* __restrict__ wb)
{
  int bid = blockIdx.x;            // 2 layers * 4 C * 16 g = 128 blocks
  int layer = bid >> 6, rest = bid & 63;
  int C = rest >> 4, g = rest & 15;
  int lane = threadIdx.x;
  int m = lane & 15, q = lane >> 4;
  int dim = g*16 + m;
  const float* W = layer ? (dim < 128 ? Wl2 : Wr2) : (dim < 128 ? Wl1 : Wr1);
  int dcol = dim & 127;
  _Float16 h[8];
  #pragma unroll
  for (int j = 0; j < 8; j++) {
    int k = C*32 + q*8 + j;
    h[j] = (_Float16)W[(size_t)k*DIM + dcol];
  }
  size_t off = ((size_t)bid*64 + lane)*8;
  *(hfrag8*)(wb + off) = *(hfrag8*)h;
}

// ---------------- MFMA dual GEMM (fp16 single-MFMA) ----------------
// Wave = 16 nodes x 256 combined dims. One f16 MFMA per 16x16 tile.
// TIN=float: cvt x on the fly. TIN=_Float16: raw uint4 frag loads.
template<typename TIN>
__global__ __launch_bounds__(256) void gemm_mfma(
    const TIN* __restrict__ x,
    const _Float16* __restrict__ wb,
    const float* __restrict__ bl, const float* __restrict__ br,
    __half* __restrict__ xlh, __half* __restrict__ xrh)
{
  __shared__ float lds[4][16*LROW2];   // 33.8 KB
  int wv = threadIdx.x >> 6, lane = threadIdx.x & 63;
  int G = blockIdx.x * 4 + wv;
  if (G >= NGROUPS) return;

  int m = lane & 15, q = lane >> 4;
  const TIN* xrow = x + (size_t)(G*16 + m)*DIM + q*8;

  f32x4 acc[16];
  #pragma unroll
  for (int g = 0; g < 16; g++) acc[g] = (f32x4)(0.f);

  #pragma unroll 1
  for (int C = 0; C < 4; C++) {
    hfrag8 ah;
    if constexpr (sizeof(TIN) == 4) {
      float v[8];
      *(float4*)(v)     = *(const float4*)((const float*)xrow + C*32);
      *(float4*)(v + 4) = *(const float4*)((const float*)xrow + C*32 + 4);
      _Float16 hh[8];
      #pragma unroll
      for (int j = 0; j < 8; j++) hh[j] = (_Float16)v[j];
      ah = *(hfrag8*)hh;
    } else {
      ah = *(const hfrag8*)((const _Float16*)xrow + C*32);
    }
    #pragma unroll
    for (int g = 0; g < 16; g++) {
      size_t boff = ((size_t)(C*16 + g)*64 + lane)*8;
      hfrag8 bh = *(const hfrag8*)(wb + boff);
      acc[g] = __builtin_amdgcn_mfma_f32_16x16x32_f16(ah, bh, acc[g], 0, 0, 0);
    }
  }

  // C/D: col = lane&15 (dim), row = (lane>>4)*4 + reg (node). LDS transpose.
  float* wlds = lds[wv];
  int dcol = (lane & 31) * 4;
  int rowsel = lane >> 5;
  #pragma unroll
  for (int half = 0; half < 2; half++) {
    #pragma unroll
    for (int g = 0; g < 8; g++) {
      #pragma unroll
      for (int r = 0; r < 4; r++)
        wlds[(q*4 + r)*LROW2 + g*16 + m] = acc[half*8 + g][r];
    }
    const float* B = half ? br : bl;
    ushort* outh = half ? (ushort*)xrh : (ushort*)xlh;
    float4 bv = *(const float4*)(B + dcol);
    #pragma unroll
    for (int it = 0; it < 8; it++) {
      int i = it*2 + rowsel;
      float4 vv = *(const float4*)(wlds + i*LROW2 + dcol);
      int node = G*16 + i;
      __half2 h0 = __floats2half2_rn(vv.x + bv.x, vv.y + bv.y);
      __half2 h1 = __floats2half2_rn(vv.z + bv.z, vv.w + bv.w);
      uint2 pk = make_uint2(*(uint*)&h0, *(uint*)&h1);
      *(uint2*)(outh + (size_t)node*DIM + dcol) = pk;
    }
  }
}

// ---------------- fused edge phase: 16 lanes/node, 4 nodes/wave ------------
// Packed fp16 math; OUT==1 writes fp16 rows (next layer input), OUT==0 fp32.
template<int OUT>
__global__ __launch_bounds__(256) void gat_gather(
    const __half* __restrict__ xlh, const __half* __restrict__ xrh,
    const int* __restrict__ row_start, const int* __restrict__ csr_src,
    const float* __restrict__ att, const float* __restrict__ bias,
    float* __restrict__ outf, __half* __restrict__ outh)
{
  int wave = (blockIdx.x * 256 + threadIdx.x) >> 6;
  int lane = threadIdx.x & 63;
  int q4 = lane >> 4;
  int hl = lane & 15;
  int node = wave * 4 + q4;           // N = 50000 = 12500 waves * 4, exact
  int r0 = row_start[node];
  int deg = row_start[node + 1] - r0;
  int last = r0 + deg - 1;
  int d1 = max(deg, __shfl_xor(deg, 16, 64));
  int dmax = max(d1, __shfl_xor(d1, 32, 64));

  uint4 rx = *(const uint4*)((const ushort*)xrh + (size_t)node*DIM + hl*8);
  h2 xr01 = u2h(rx.x), xr23 = u2h(rx.y), xr45 = u2h(rx.z), xr67 = u2h(rx.w);
  const float* ap = att + hl*8;
  float4 af0 = *(const float4*)(ap);
  float4 af1 = *(const float4*)(ap + 4);
  h2 a01 = {(_Float16)af0.x, (_Float16)af0.y};
  h2 a23 = {(_Float16)af0.z, (_Float16)af0.w};
  h2 a45 = {(_Float16)af1.x, (_Float16)af1.y};
  h2 a67 = {(_Float16)af1.z, (_Float16)af1.w};
  const h2 c02 = {(_Float16)0.2f, (_Float16)0.2f};

  float l = 0.f;
  float b0a=0,b1a=0,b2a=0,b3a=0,b4a=0,b5a=0,b6a=0,b7a=0;
  const ushort* xbase = (const ushort*)xlh + hl*8;

  for (int t = 0; t < dmax; t += 4) {
    uint4 raw[4];
    #pragma unroll
    for (int j = 0; j < 4; j++) {
      int rr = r0 + t + j;
      int rc = rr <= last ? rr : last;
      rc = rc >= 0 ? rc : 0;                  // deg==0 safety
      int si = csr_src[rc];
      raw[j] = *(const uint4*)(xbase + (size_t)si*DIM);
    }
    #pragma unroll
    for (int j = 0; j < 4; j++) {
      h2 v01 = u2h(raw[j].x), v23 = u2h(raw[j].y);
      h2 v45 = u2h(raw[j].z), v67 = u2h(raw[j].w);
      h2 s01 = v01 + xr01, s23 = v23 + xr23;
      h2 s45 = v45 + xr45, s67 = v67 + xr67;
      s01 = __builtin_elementwise_max(s01, s01 * c02);
      s23 = __builtin_elementwise_max(s23, s23 * c02);
      s45 = __builtin_elementwise_max(s45, s45 * c02);
      s67 = __builtin_elementwise_max(s67, s67 * c02);
      float p = __builtin_amdgcn_fdot2(s01, a01, 0.f, false);
      p = __builtin_amdgcn_fdot2(s23, a23, p, false);
      p = __builtin_amdgcn_fdot2(s45, a45, p, false);
      p = __builtin_amdgcn_fdot2(s67, a67, p, false);
      #pragma unroll
      for (int o = 1; o <= 8; o <<= 1) p += __shfl_xor(p, o, 64);
      float w = (t + j < deg) ? __expf(p) : 0.f;
      l += w;
      b0a = fmaf(w, (float)v01.x, b0a); b1a = fmaf(w, (float)v01.y, b1a);
      b2a = fmaf(w, (float)v23.x, b2a); b3a = fmaf(w, (float)v23.y, b3a);
      b4a = fmaf(w, (float)v45.x, b4a); b5a = fmaf(w, (float)v45.y, b5a);
      b6a = fmaf(w, (float)v67.x, b6a); b7a = fmaf(w, (float)v67.y, b7a);
    }
  }

  float inv = 1.f / fmaxf(l, 1e-16f);
  const float* bp = bias + hl*8;
  float4 c0 = *(const float4*)(bp);
  float4 c1 = *(const float4*)(bp + 4);
  float4 o0, o1;
  o0.x = fmaxf(fmaf(b0a, inv, c0.x), 0.f);
  o0.y = fmaxf(fmaf(b1a, inv, c0.y), 0.f);
  o0.z = fmaxf(fmaf(b2a, inv, c0.z), 0.f);
  o0.w = fmaxf(fmaf(b3a, inv, c0.w), 0.f);
  o1.x = fmaxf(fmaf(b4a, inv, c1.x), 0.f);
  o1.y = fmaxf(fmaf(b5a, inv, c1.y), 0.f);
  o1.z = fmaxf(fmaf(b6a, inv, c1.z), 0.f);
  o1.w = fmaxf(fmaf(b7a, inv, c1.w), 0.f);
  if (OUT == 0) {
    float* op = outf + (size_t)node*DIM + hl*8;
    *(float4*)(op)     = o0;
    *(float4*)(op + 4) = o1;
  } else {
    __half2 h0 = __floats2half2_rn(o0.x, o0.y);
    __half2 h1 = __floats2half2_rn(o0.z, o0.w);
    __half2 h2v = __floats2half2_rn(o1.x, o1.y);
    __half2 h3 = __floats2half2_rn(o1.z, o1.w);
    uint4 pk = make_uint4(*(uint*)&h0, *(uint*)&h1, *(uint*)&h2v, *(uint*)&h3);
    *(uint4*)((ushort*)outh + (size_t)node*DIM + hl*8) = pk;
  }
}

extern "C" void kernel_launch(void* const* d_in, const int* in_sizes, int n_in,
                              void* d_out, int out_size, void* d_ws, size_t ws_size,
                              hipStream_t stream)
{
  const float* node_fts = (const float*)d_in[0];
  const int*  edge_index = (const int*)d_in[1];
  const float* Wl1 = (const float*)d_in[2];
  const float* bl1 = (const float*)d_in[3];
  const float* Wr1 = (const float*)d_in[4];
  const float* br1 = (const float*)d_in[5];
  const float* att1 = (const float*)d_in[6];
  const float* bias1 = (const float*)d_in[7];
  const float* Wl2 = (const float*)d_in[8];
  const float* bl2 = (const float*)d_in[9];
  const float* Wr2 = (const float*)d_in[10];
  const float* br2 = (const float*)d_in[11];
  const float* att2 = (const float*)d_in[12];
  const float* bias2 = (const float*)d_in[13];
  const int* src = edge_index;
  const int* dst = edge_index + N_EDGES;

  char* ws = (char*)d_ws;
  __half* xlh = (__half*)ws;               ws += (size_t)N_NODES*DIM*2;
  __half* xrh = (__half*)ws;               ws += (size_t)N_NODES*DIM*2;
  __half* hh  = (__half*)ws;               ws += (size_t)N_NODES*DIM*2;
  _Float16* wb = (_Float16*)ws;            ws += 2*4*16*64*8*2;
  int* row_start   = (int*)ws;             ws += (N_NODES+1)*4;
  int* csr_src     = (int*)ws;             ws += (size_t)N_EDGES*4;
  int* bucket_cnt  = (int*)ws;             ws += KBUCKET*4;
  uint2* bucketdata = (uint2*)ws;          ws += (size_t)KBUCKET*BCAP*8;

  const int W_LAYER = 4*16*64*8;           // fp16 elems per layer of wb

  int gemm_blocks = (NGROUPS + 3) / 4;
  int gather_blocks = N_NODES / 16;        // 4 waves/block, 4 nodes/wave

  // ---- CSR build (two-phase bucket radix) ----
  hipMemsetAsync(bucket_cnt, 0, KBUCKET * sizeof(int), stream);
  bucket_scatter_k<<<N_EDGES/EPB, 256, 0, stream>>>(src, dst, bucket_cnt, bucketdata);
  bucket_csr_k<<<KBUCKET, 256, 0, stream>>>(bucket_cnt, bucketdata, row_start, csr_src);

  // ---- W fragment prep ----
  prep_w<<<128, 64, 0, stream>>>(Wl1, Wr1, Wl2, Wr2, wb);

  // ---- layer 1 ----
  gemm_mfma<float><<<gemm_blocks, 256, 0, stream>>>(node_fts, wb, bl1, br1, xlh, xrh);
  gat_gather<1><<<gather_blocks, 256, 0, stream>>>(xlh, xrh, row_start, csr_src,
                                                   att1, bias1, nullptr, hh);
  // ---- layer 2 ----
  gemm_mfma<_Float16><<<gemm_blocks, 256, 0, stream>>>((const _Float16*)hh,
                                             wb + W_LAYER, bl2, br2, xlh, xrh);
  gat_gather<0><<<gather_blocks, 256, 0, stream>>>(xlh, xrh, row_start, csr_src,
                                                   att2, bias2, (float*)d_out, nullptr);
}